// Round 2
// baseline (3701.284 us; speedup 1.0000x reference)
//
#include <hip/hip_runtime.h>
#include <math.h>

#define NN 2048
#define EE 32768
#define CAP 256

// ---------------- RW-PE graph kernels ----------------

__global__ __launch_bounds__(256) void scatter_edges(const int* __restrict__ ei, float* __restrict__ A){
  int e = blockIdx.x*256 + threadIdx.x;
  if (e >= EE) return;
  int s = ei[e], t = ei[EE + e];
  atomicAdd(&A[(size_t)s*NN + t], 1.0f);
  atomicAdd(&A[(size_t)t*NN + s], 1.0f);
}

// deg = clip(rowsum,1); T = A/deg in place; rw[:,0] = diag(T)
__global__ __launch_bounds__(256) void row_norm(float* __restrict__ A, float* __restrict__ rw){
  __shared__ float sbuf[4];
  int i = blockIdx.x, t = threadIdx.x;
  float s = 0.f;
  for (int m = t; m < NN; m += 256) s += A[(size_t)i*NN + m];
  for (int w = 32; w >= 1; w >>= 1) s += __shfl_xor(s, w, 64);
  if ((t & 63) == 0) sbuf[t >> 6] = s;
  __syncthreads();
  s = sbuf[0] + sbuf[1] + sbuf[2] + sbuf[3];
  float inv = 1.0f / fmaxf(s, 1.0f);
  for (int m = t; m < NN; m += 256){
    float v = A[(size_t)i*NN + m] * inv;
    A[(size_t)i*NN + m] = v;
    if (m == i) rw[i*8 + 0] = v;
  }
}

// CSC of T via symmetry of A's pattern: col j entries = {m : T[j,m]!=0}, val = T[m,j]
__global__ __launch_bounds__(256) void build_csc(const float* __restrict__ T, float* __restrict__ cscv,
                                                 int* __restrict__ cscm, int* __restrict__ cnt){
  __shared__ int scnt;
  int j = blockIdx.x, t = threadIdx.x;
  if (t == 0) scnt = 0;
  __syncthreads();
  for (int m = t; m < NN; m += 256){
    float tv = T[(size_t)j*NN + m];
    if (tv != 0.f){
      int p = atomicAdd(&scnt, 1);
      if (p < CAP){
        cscm[j*CAP + p] = m;
        cscv[j*CAP + p] = T[(size_t)m*NN + j];
      }
    }
  }
  __syncthreads();
  if (t == 0) cnt[j] = min(scnt, CAP);
}

// Tn = Tk @ T (T sparse, via CSC). 4 rows per block. Harvest diag into rw[:,kidx].
__global__ __launch_bounds__(256) void spmm4(const float* __restrict__ Tk, const float* __restrict__ cscv,
                                             const int* __restrict__ cscm, const int* __restrict__ cnt,
                                             float* __restrict__ Tn, float* __restrict__ rw, int kidx){
  __shared__ float tk[4][NN + 4];
  int i0 = blockIdx.x*4, t = threadIdx.x;
  for (int r = 0; r < 4; r++){
    for (int m4 = t; m4 < NN/4; m4 += 256){
      float4 v = *(const float4*)&Tk[(size_t)(i0+r)*NN + m4*4];
      tk[r][m4*4+0] = v.x; tk[r][m4*4+1] = v.y; tk[r][m4*4+2] = v.z; tk[r][m4*4+3] = v.w;
    }
  }
  __syncthreads();
  for (int j = t; j < NN; j += 256){
    int n = cnt[j];
    const int*   im = &cscm[j*CAP];
    const float* iv = &cscv[j*CAP];
    float a0=0.f,a1=0.f,a2=0.f,a3=0.f;
    for (int c = 0; c < n; c++){
      int m = im[c]; float v = iv[c];
      a0 += v*tk[0][m]; a1 += v*tk[1][m]; a2 += v*tk[2][m]; a3 += v*tk[3][m];
    }
    Tn[(size_t)(i0+0)*NN + j] = a0;
    Tn[(size_t)(i0+1)*NN + j] = a1;
    Tn[(size_t)(i0+2)*NN + j] = a2;
    Tn[(size_t)(i0+3)*NN + j] = a3;
    if (j == i0+0) rw[j*8 + kidx] = a0;
    if (j == i0+1) rw[j*8 + kidx] = a1;
    if (j == i0+2) rw[j*8 + kidx] = a2;
    if (j == i0+3) rw[j*8 + kidx] = a3;
  }
}

// pe = rw @ W_rwpe + b  (2048x8 @ 8x16)
__global__ __launch_bounds__(256) void pe_kernel(const float* __restrict__ rw, const float* __restrict__ W,
                                                 const float* __restrict__ b, float* __restrict__ pe){
  int idx = blockIdx.x*256 + threadIdx.x;
  if (idx >= NN*16) return;
  int i = idx >> 4, c = idx & 15;
  float acc = b[c];
  #pragma unroll
  for (int k = 0; k < 8; k++) acc += rw[i*8+k] * W[k*16+c];
  pe[idx] = acc;
}

// pp_all[l,j,h] = pe[j,:] @ Wpe[l] + bpe[l]   (all 3 layers)
__global__ __launch_bounds__(256) void pp_kernel(const float* __restrict__ pe, const float* __restrict__ Wpe,
                                                 const float* __restrict__ bpe, float* __restrict__ pp){
  int idx = blockIdx.x*256 + threadIdx.x;
  if (idx >= 3*NN*12) return;
  int l = idx / (NN*12);
  int rm = idx % (NN*12);
  int j = rm / 12, h = rm % 12;
  float acc = bpe[l*12 + h];
  #pragma unroll
  for (int c = 0; c < 16; c++) acc += pe[j*16+c] * Wpe[(l*16+c)*12 + h];
  pp[idx] = acc;
}

// ---------------- f32 GEMM: C = A@B + bias (opt. exact GELU) ----------------
// Tile: (TM*16) x 128, BK=16, 256 threads, TM x 8 per thread.
// B-tile layout: slot c stored at bcol(c)=c*8+((c>>3)&1)*4 -> per-instr bank use is
// uniform 2-way (free, m136) instead of 4-way, all accesses stay 16B-aligned.
template<int DOGELU, int TM>
__global__ __launch_bounds__(256) void gemm_bias(const float* __restrict__ A, const float* __restrict__ B,
                                                 const float* __restrict__ bias, float* __restrict__ C,
                                                 int N, int K){
  __shared__ float As[16][TM*16 + 4];
  __shared__ float Bs[16][132];
  const int bm = blockIdx.y * (TM*16), bn = blockIdx.x * 128;
  const int t = threadIdx.x;
  const int r = t >> 4, c = t & 15;
  const int bcol = c*8 + ((c>>3)&1)*4;
  float acc[TM][8];
  #pragma unroll
  for (int i = 0; i < TM; i++)
    #pragma unroll
    for (int j = 0; j < 8; j++) acc[i][j] = 0.f;
  const int am = t >> 2, ak = (t & 3) * 4;
  const int bk = t >> 4, bn2 = (t & 15) * 8;
  const int wcol = bn2 + ((bn2 >> 6) & 1) * 4 - ((bn2>>3)>=8 ? ((bn2>>3)*8 - bcol) - ((bn2>>3)*8 - bcol) : 0); // == bcol of this thread
  (void)wcol;
  for (int k0 = 0; k0 < K; k0 += 16){
    float4 a0, a1;
    a0 = *(const float4*)&A[(size_t)(bm+am)*K + k0 + ak];
    if constexpr (TM == 8) a1 = *(const float4*)&A[(size_t)(bm+am+64)*K + k0 + ak];
    float4 b0 = *(const float4*)&B[(size_t)(k0+bk)*N + bn + bn2];
    float4 b1 = *(const float4*)&B[(size_t)(k0+bk)*N + bn + bn2 + 4];
    __syncthreads();
    As[ak+0][am] = a0.x; As[ak+1][am] = a0.y; As[ak+2][am] = a0.z; As[ak+3][am] = a0.w;
    if constexpr (TM == 8){
      As[ak+0][am+64] = a1.x; As[ak+1][am+64] = a1.y; As[ak+2][am+64] = a1.z; As[ak+3][am+64] = a1.w;
    }
    *(float4*)&Bs[bk][bcol]     = b0;   // writer c == reader c == t&15
    *(float4*)&Bs[bk][bcol + 4] = b1;
    __syncthreads();
    #pragma unroll
    for (int k = 0; k < 16; k++){
      float ar[TM], br[8];
      float4 arv0 = *(const float4*)&As[k][r*TM];
      ar[0]=arv0.x; ar[1]=arv0.y; ar[2]=arv0.z; ar[3]=arv0.w;
      if constexpr (TM == 8){
        float4 arv1 = *(const float4*)&As[k][r*TM + 4];
        ar[4]=arv1.x; ar[5]=arv1.y; ar[6]=arv1.z; ar[7]=arv1.w;
      }
      float4 brv0 = *(const float4*)&Bs[k][bcol];
      float4 brv1 = *(const float4*)&Bs[k][bcol + 4];
      br[0]=brv0.x; br[1]=brv0.y; br[2]=brv0.z; br[3]=brv0.w;
      br[4]=brv1.x; br[5]=brv1.y; br[6]=brv1.z; br[7]=brv1.w;
      #pragma unroll
      for (int i = 0; i < TM; i++)
        #pragma unroll
        for (int j = 0; j < 8; j++)
          acc[i][j] += ar[i]*br[j];
    }
  }
  #pragma unroll
  for (int i = 0; i < TM; i++){
    float o[8];
    #pragma unroll
    for (int j = 0; j < 8; j++){
      o[j] = acc[i][j] + bias[bn + c*8 + j];
      if (DOGELU) o[j] = 0.5f*o[j]*(1.f + erff(o[j]*0.70710678118f));
    }
    float4 o0 = {o[0],o[1],o[2],o[3]}, o1 = {o[4],o[5],o[6],o[7]};
    *(float4*)&C[(size_t)(bm + r*TM + i)*N + bn + c*8]     = o0;
    *(float4*)&C[(size_t)(bm + r*TM + i)*N + bn + c*8 + 4] = o1;
  }
}

// ---------------- flash attention, f32, bias pp[j,h] (row term cancels in softmax) ----
// grid (32 qblocks, 12 heads), 256 thr, 64x64 tiles. K-buffer reused for P.
// LDS layout: stride-64 rows + XOR swizzle on 4-float groups: grp ^= (row>>2)&7.
// All inner-loop accesses are b128, analyzed broadcast or uniform 2-way (free).
#define SWZ(row, grp) ((((grp) ^ (((row) >> 2) & 7)) << 2))

__global__ __launch_bounds__(256) void attn_f32(const float* __restrict__ qkv, const float* __restrict__ pp,
                                                float* __restrict__ outp){
  __shared__ float qs[64*64];
  __shared__ float ks[64*64];   // K tile, then reused for P
  __shared__ float vs[64*64];
  __shared__ float ppj[64];
  int h = blockIdx.y;
  int i0 = blockIdx.x * 64;
  int t = threadIdx.x;
  int r = t >> 4, c = t & 15;
  #pragma unroll
  for (int p = 0; p < 4; p++){
    int row = (t >> 4) + p*16;
    int kg  = t & 15;
    float4 q4 = *(const float4*)&qkv[(size_t)(i0+row)*2304 + h*64 + kg*4];
    q4.x *= 0.125f; q4.y *= 0.125f; q4.z *= 0.125f; q4.w *= 0.125f;
    *(float4*)&qs[row*64 + SWZ(row, kg)] = q4;
  }
  float mrow[4], lrow[4], acc[4][4];
  #pragma unroll
  for (int ii = 0; ii < 4; ii++){
    mrow[ii] = -1e30f; lrow[ii] = 0.f;
    #pragma unroll
    for (int dd = 0; dd < 4; dd++) acc[ii][dd] = 0.f;
  }
  for (int j0 = 0; j0 < NN; j0 += 64){
    __syncthreads();   // prior tile's PV reads of ks/vs complete
    #pragma unroll
    for (int p = 0; p < 4; p++){
      int row = (t >> 4) + p*16;
      int kg  = t & 15;
      float4 k4 = *(const float4*)&qkv[(size_t)(j0+row)*2304 + 768  + h*64 + kg*4];
      float4 v4 = *(const float4*)&qkv[(size_t)(j0+row)*2304 + 1536 + h*64 + kg*4];
      *(float4*)&ks[row*64 + SWZ(row, kg)] = k4;
      *(float4*)&vs[row*64 + SWZ(row, kg)] = v4;
    }
    if (t < 64) ppj[t] = pp[(size_t)(j0+t)*12 + h];
    __syncthreads();
    float s[4][4];
    #pragma unroll
    for (int ii=0;ii<4;ii++)
      #pragma unroll
      for (int jj=0;jj<4;jj++) s[ii][jj]=0.f;
    #pragma unroll 4
    for (int kg = 0; kg < 16; kg++){
      float4 a4[4], b4[4];
      #pragma unroll
      for (int ii = 0; ii < 4; ii++) a4[ii] = *(const float4*)&qs[(r*4+ii)*64 + SWZ(r*4+ii, kg)];
      #pragma unroll
      for (int jj = 0; jj < 4; jj++) b4[jj] = *(const float4*)&ks[(c*4+jj)*64 + SWZ(c*4+jj, kg)];
      #pragma unroll
      for (int ii = 0; ii < 4; ii++)
        #pragma unroll
        for (int jj = 0; jj < 4; jj++)
          s[ii][jj] += a4[ii].x*b4[jj].x + a4[ii].y*b4[jj].y + a4[ii].z*b4[jj].z + a4[ii].w*b4[jj].w;
    }
    float mx[4];
    #pragma unroll
    for (int ii = 0; ii < 4; ii++){
      s[ii][0]+=ppj[c*4+0]; s[ii][1]+=ppj[c*4+1]; s[ii][2]+=ppj[c*4+2]; s[ii][3]+=ppj[c*4+3];
      mx[ii] = fmaxf(fmaxf(s[ii][0],s[ii][1]), fmaxf(s[ii][2],s[ii][3]));
    }
    #pragma unroll
    for (int w = 1; w < 16; w <<= 1){
      #pragma unroll
      for (int ii = 0; ii < 4; ii++) mx[ii] = fmaxf(mx[ii], __shfl_xor(mx[ii], w, 64));
    }
    float al[4], rs[4];
    #pragma unroll
    for (int ii = 0; ii < 4; ii++){
      float mn = fmaxf(mrow[ii], mx[ii]);
      al[ii] = expf(mrow[ii] - mn);
      mrow[ii] = mn;
      float ssum = 0.f;
      #pragma unroll
      for (int jj = 0; jj < 4; jj++){ s[ii][jj] = expf(s[ii][jj] - mn); ssum += s[ii][jj]; }
      rs[ii] = ssum;
    }
    #pragma unroll
    for (int w = 1; w < 16; w <<= 1){
      #pragma unroll
      for (int ii = 0; ii < 4; ii++) rs[ii] += __shfl_xor(rs[ii], w, 64);
    }
    #pragma unroll
    for (int ii = 0; ii < 4; ii++){
      lrow[ii] = lrow[ii]*al[ii] + rs[ii];
      #pragma unroll
      for (int dd = 0; dd < 4; dd++) acc[ii][dd] *= al[ii];
    }
    __syncthreads();  // score-phase reads of ks done before P overwrite
    #pragma unroll
    for (int ii=0;ii<4;ii++)
      #pragma unroll
      for (int jj=0;jj<4;jj++) ks[(r*4+ii)*64 + SWZ(r*4+ii, c) + jj] = s[ii][jj];
    __syncthreads();
    #pragma unroll 4
    for (int jg = 0; jg < 16; jg++){
      float4 p4[4], v40, v41, v42, v43;
      #pragma unroll
      for (int ii = 0; ii < 4; ii++) p4[ii] = *(const float4*)&ks[(r*4+ii)*64 + SWZ(r*4+ii, jg)];
      v40 = *(const float4*)&vs[(jg*4+0)*64 + SWZ(jg*4+0, c)];
      v41 = *(const float4*)&vs[(jg*4+1)*64 + SWZ(jg*4+1, c)];
      v42 = *(const float4*)&vs[(jg*4+2)*64 + SWZ(jg*4+2, c)];
      v43 = *(const float4*)&vs[(jg*4+3)*64 + SWZ(jg*4+3, c)];
      #pragma unroll
      for (int ii = 0; ii < 4; ii++){
        acc[ii][0] += p4[ii].x*v40.x + p4[ii].y*v41.x + p4[ii].z*v42.x + p4[ii].w*v43.x;
        acc[ii][1] += p4[ii].x*v40.y + p4[ii].y*v41.y + p4[ii].z*v42.y + p4[ii].w*v43.y;
        acc[ii][2] += p4[ii].x*v40.z + p4[ii].y*v41.z + p4[ii].z*v42.z + p4[ii].w*v43.z;
        acc[ii][3] += p4[ii].x*v40.w + p4[ii].y*v41.w + p4[ii].z*v42.w + p4[ii].w*v43.w;
      }
    }
  }
  #pragma unroll
  for (int ii = 0; ii < 4; ii++){
    float invl = 1.0f / lrow[ii];
    float4 o = {acc[ii][0]*invl, acc[ii][1]*invl, acc[ii][2]*invl, acc[ii][3]*invl};
    *(float4*)&outp[(size_t)(i0 + r*4 + ii)*768 + h*64 + c*4] = o;
  }
}

// ---------------- residual add + LayerNorm ----------------
__global__ __launch_bounds__(256) void add_ln(const float* __restrict__ X, const float* __restrict__ R,
                                              const float* __restrict__ g, const float* __restrict__ b,
                                              float* __restrict__ Y){
  __shared__ float sbuf[4];
  int i = blockIdx.x, t = threadIdx.x;
  float x0 = X[(size_t)i*768 + t]       + R[(size_t)i*768 + t];
  float x1 = X[(size_t)i*768 + t + 256] + R[(size_t)i*768 + t + 256];
  float x2 = X[(size_t)i*768 + t + 512] + R[(size_t)i*768 + t + 512];
  float s = x0 + x1 + x2;
  for (int w = 32; w >= 1; w >>= 1) s += __shfl_xor(s, w, 64);
  if ((t & 63) == 0) sbuf[t >> 6] = s;
  __syncthreads();
  s = sbuf[0] + sbuf[1] + sbuf[2] + sbuf[3];
  float mean = s * (1.0f/768.0f);
  float d0 = x0-mean, d1 = x1-mean, d2 = x2-mean;
  float vv = d0*d0 + d1*d1 + d2*d2;
  __syncthreads();
  for (int w = 32; w >= 1; w >>= 1) vv += __shfl_xor(vv, w, 64);
  if ((t & 63) == 0) sbuf[t >> 6] = vv;
  __syncthreads();
  vv = sbuf[0] + sbuf[1] + sbuf[2] + sbuf[3];
  float inv = 1.0f / sqrtf(vv*(1.0f/768.0f) + 1e-5f);
  Y[(size_t)i*768 + t]       = d0*inv*g[t]     + b[t];
  Y[(size_t)i*768 + t + 256] = d1*inv*g[t+256] + b[t+256];
  Y[(size_t)i*768 + t + 512] = d2*inv*g[t+512] + b[t+512];
}

// ---------------- launcher ----------------
extern "C" void kernel_launch(void* const* d_in, const int* in_sizes, int n_in,
                              void* d_out, int out_size, void* d_ws, size_t ws_size,
                              hipStream_t stream) {
  const float* nf     = (const float*)d_in[0];
  const int*   ei     = (const int*)  d_in[1];
  const float* W_rwpe = (const float*)d_in[2];
  const float* b_rwpe = (const float*)d_in[3];
  const float* Wqkv   = (const float*)d_in[4];
  const float* bqkv   = (const float*)d_in[5];
  const float* Wpe    = (const float*)d_in[6];
  const float* bpe    = (const float*)d_in[7];
  const float* Wout   = (const float*)d_in[8];
  const float* bout   = (const float*)d_in[9];
  const float* W1     = (const float*)d_in[10];
  const float* b1     = (const float*)d_in[11];
  const float* W2     = (const float*)d_in[12];
  const float* b2     = (const float*)d_in[13];
  const float* g1     = (const float*)d_in[14];
  const float* be1    = (const float*)d_in[15];
  const float* g2     = (const float*)d_in[16];
  const float* be2    = (const float*)d_in[17];
  float* out = (float*)d_out;

  char* w = (char*)d_ws;
  size_t off = 0;
  auto alloc = [&](size_t bytes){ void* p = w + off; off += (bytes + 255) & ~(size_t)255; return p; };
  float* P0    = (float*)alloc((size_t)NN*NN*4);     // A -> T -> odd powers
  float* P1    = (float*)alloc((size_t)NN*NN*4);     // even powers
  float* cscv  = (float*)alloc((size_t)NN*CAP*4);
  int*   cscm  = (int*)  alloc((size_t)NN*CAP*4);
  int*   cnt   = (int*)  alloc((size_t)NN*4);
  float* rw    = (float*)alloc((size_t)NN*8*4);
  float* pe    = (float*)alloc((size_t)NN*16*4);
  float* pp    = (float*)alloc((size_t)3*NN*12*4);
  float* qkvb  = (float*)alloc((size_t)NN*2304*4);
  float* attnb = (float*)alloc((size_t)NN*768*4);
  float* projb = (float*)alloc((size_t)NN*768*4);
  float* h1    = (float*)alloc((size_t)NN*768*4);
  float* ffn1  = (float*)alloc((size_t)NN*3072*4);
  float* ffn2  = (float*)alloc((size_t)NN*768*4);
  float* hb    = (float*)alloc((size_t)NN*768*4);
  (void)ws_size; (void)in_sizes; (void)n_in; (void)out_size;

  // --- RW positional encoding ---
  hipMemsetAsync(P0, 0, (size_t)NN*NN*4, stream);
  scatter_edges<<<EE/256, 256, 0, stream>>>(ei, P0);
  row_norm<<<NN, 256, 0, stream>>>(P0, rw);
  build_csc<<<NN, 256, 0, stream>>>(P0, cscv, cscm, cnt);
  for (int k = 1; k < 8; k++){
    const float* src = (k & 1) ? P0 : P1;
    float*       dst = (k & 1) ? P1 : P0;
    spmm4<<<NN/4, 256, 0, stream>>>(src, cscv, cscm, cnt, dst, rw, k);
  }
  pe_kernel<<<NN*16/256, 256, 0, stream>>>(rw, W_rwpe, b_rwpe, pe);
  pp_kernel<<<3*NN*12/256, 256, 0, stream>>>(pe, Wpe, bpe, pp);

  // --- transformer layers ---
  const float* h = nf;
  for (int l = 0; l < 3; l++){
    gemm_bias<0,8><<<dim3(2304/128, 2048/128), 256, 0, stream>>>(h, Wqkv + (size_t)l*768*2304, bqkv + (size_t)l*2304, qkvb, 2304, 768);
    attn_f32<<<dim3(NN/64, 12), 256, 0, stream>>>(qkvb, pp + (size_t)l*NN*12, attnb);
    gemm_bias<0,4><<<dim3(768/128, 2048/64), 256, 0, stream>>>(attnb, Wout + (size_t)l*768*768, bout + (size_t)l*768, projb, 768, 768);
    add_ln<<<NN, 256, 0, stream>>>(projb, h, g1 + (size_t)l*768, be1 + (size_t)l*768, h1);
    gemm_bias<1,8><<<dim3(3072/128, 2048/128), 256, 0, stream>>>(h1, W1 + (size_t)l*768*3072, b1 + (size_t)l*3072, ffn1, 3072, 768);
    gemm_bias<0,4><<<dim3(768/128, 2048/64), 256, 0, stream>>>(ffn1, W2 + (size_t)l*3072*768, b2 + (size_t)l*768, ffn2, 768, 3072);
    float* hout = (l == 2) ? out : hb;
    add_ln<<<NN, 256, 0, stream>>>(ffn2, h1, g2 + (size_t)l*768, be2 + (size_t)l*768, hout);
    h = hout;
  }
}

// Round 3
// 2476.534 us; speedup vs baseline: 1.4945x; 1.4945x over previous
//
#include <hip/hip_runtime.h>
#include <math.h>

#define NN 2048
#define EE 32768
#define CAP 256

typedef __attribute__((ext_vector_type(8))) short bf16x8;
typedef __attribute__((ext_vector_type(4))) float f32x4;
typedef __attribute__((ext_vector_type(8))) unsigned short u16x8;
typedef __attribute__((ext_vector_type(4))) unsigned short u16x4;

__device__ inline unsigned short f2bu(float x){
  unsigned u = __builtin_bit_cast(unsigned, x);
  return (unsigned short)((u + 0x7fffu + ((u>>16)&1u)) >> 16);
}
__device__ inline float bu2f(unsigned short h){
  unsigned u = ((unsigned)h) << 16;
  return __builtin_bit_cast(float, u);
}
// LDS offset (in ushorts) for (row, kgrp) with bank-spreading swizzle.
__device__ inline int swz8(int row, int kg){ return row*32 + ((kg ^ ((row>>1)&3))<<3); }

// ---------------- RW-PE graph kernels ----------------

__global__ __launch_bounds__(256) void scatter_edges(const int* __restrict__ ei, float* __restrict__ A){
  int e = blockIdx.x*256 + threadIdx.x;
  if (e >= EE) return;
  int s = ei[e], t = ei[EE + e];
  atomicAdd(&A[(size_t)s*NN + t], 1.0f);
  atomicAdd(&A[(size_t)t*NN + s], 1.0f);
}

__global__ __launch_bounds__(256) void row_norm(float* __restrict__ A, float* __restrict__ rw){
  __shared__ float sbuf[4];
  int i = blockIdx.x, t = threadIdx.x;
  float s = 0.f;
  for (int m = t; m < NN; m += 256) s += A[(size_t)i*NN + m];
  for (int w = 32; w >= 1; w >>= 1) s += __shfl_xor(s, w, 64);
  if ((t & 63) == 0) sbuf[t >> 6] = s;
  __syncthreads();
  s = sbuf[0] + sbuf[1] + sbuf[2] + sbuf[3];
  float inv = 1.0f / fmaxf(s, 1.0f);
  for (int m = t; m < NN; m += 256){
    float v = A[(size_t)i*NN + m] * inv;
    A[(size_t)i*NN + m] = v;
    if (m == i) rw[i*8 + 0] = v;
  }
}

__global__ __launch_bounds__(256) void build_csc(const float* __restrict__ T, float* __restrict__ cscv,
                                                 int* __restrict__ cscm, int* __restrict__ cnt){
  __shared__ int scnt;
  int j = blockIdx.x, t = threadIdx.x;
  if (t == 0) scnt = 0;
  __syncthreads();
  for (int m = t; m < NN; m += 256){
    float tv = T[(size_t)j*NN + m];
    if (tv != 0.f){
      int p = atomicAdd(&scnt, 1);
      if (p < CAP){
        cscm[j*CAP + p] = m;
        cscv[j*CAP + p] = T[(size_t)m*NN + j];
      }
    }
  }
  __syncthreads();
  if (t == 0) cnt[j] = min(scnt, CAP);
}

__global__ __launch_bounds__(256) void spmm4(const float* __restrict__ Tk, const float* __restrict__ cscv,
                                             const int* __restrict__ cscm, const int* __restrict__ cnt,
                                             float* __restrict__ Tn, float* __restrict__ rw, int kidx){
  __shared__ float tk[4][NN + 4];
  int i0 = blockIdx.x*4, t = threadIdx.x;
  for (int r = 0; r < 4; r++){
    for (int m4 = t; m4 < NN/4; m4 += 256){
      float4 v = *(const float4*)&Tk[(size_t)(i0+r)*NN + m4*4];
      tk[r][m4*4+0] = v.x; tk[r][m4*4+1] = v.y; tk[r][m4*4+2] = v.z; tk[r][m4*4+3] = v.w;
    }
  }
  __syncthreads();
  for (int j = t; j < NN; j += 256){
    int n = cnt[j];
    const int*   im = &cscm[j*CAP];
    const float* iv = &cscv[j*CAP];
    float a0=0.f,a1=0.f,a2=0.f,a3=0.f;
    for (int c = 0; c < n; c++){
      int m = im[c]; float v = iv[c];
      a0 += v*tk[0][m]; a1 += v*tk[1][m]; a2 += v*tk[2][m]; a3 += v*tk[3][m];
    }
    Tn[(size_t)(i0+0)*NN + j] = a0;
    Tn[(size_t)(i0+1)*NN + j] = a1;
    Tn[(size_t)(i0+2)*NN + j] = a2;
    Tn[(size_t)(i0+3)*NN + j] = a3;
    if (j == i0+0) rw[j*8 + kidx] = a0;
    if (j == i0+1) rw[j*8 + kidx] = a1;
    if (j == i0+2) rw[j*8 + kidx] = a2;
    if (j == i0+3) rw[j*8 + kidx] = a3;
  }
}

__global__ __launch_bounds__(256) void pe_kernel(const float* __restrict__ rw, const float* __restrict__ W,
                                                 const float* __restrict__ b, float* __restrict__ pe){
  int idx = blockIdx.x*256 + threadIdx.x;
  if (idx >= NN*16) return;
  int i = idx >> 4, c = idx & 15;
  float acc = b[c];
  #pragma unroll
  for (int k = 0; k < 8; k++) acc += rw[i*8+k] * W[k*16+c];
  pe[idx] = acc;
}

__global__ __launch_bounds__(256) void pp_kernel(const float* __restrict__ pe, const float* __restrict__ Wpe,
                                                 const float* __restrict__ bpe, float* __restrict__ pp){
  int idx = blockIdx.x*256 + threadIdx.x;
  if (idx >= 3*NN*12) return;
  int l = idx / (NN*12);
  int rm = idx % (NN*12);
  int j = rm / 12, h = rm % 12;
  float acc = bpe[l*12 + h];
  #pragma unroll
  for (int c = 0; c < 16; c++) acc += pe[j*16+c] * Wpe[(l*16+c)*12 + h];
  pp[idx] = acc;
}

// -------- weight transpose + split-bf16 convert: W[K][N] -> T{hi,lo}[N][K] --------
__global__ __launch_bounds__(256) void wconv(const float* __restrict__ W, unsigned short* __restrict__ Thi,
                                             unsigned short* __restrict__ Tlo, int K, int N){
  __shared__ float ld[32*33];
  int k0 = blockIdx.y*32, n0 = blockIdx.x*32;
  int t = threadIdx.x;
  int r = t>>3, c4 = (t&7)*4;
  float4 v = *(const float4*)&W[(size_t)(k0+r)*N + n0 + c4];
  ld[(c4+0)*33 + r] = v.x; ld[(c4+1)*33 + r] = v.y; ld[(c4+2)*33 + r] = v.z; ld[(c4+3)*33 + r] = v.w;
  __syncthreads();
  u16x4 hi, lo;
  #pragma unroll
  for (int i = 0; i < 4; i++){
    float x = ld[r*33 + c4 + i];
    unsigned short hh = f2bu(x);
    hi[i] = hh;
    lo[i] = f2bu(x - bu2f(hh));
  }
  *(u16x4*)&Thi[(size_t)(n0+r)*K + k0 + c4] = hi;
  *(u16x4*)&Tlo[(size_t)(n0+r)*K + k0 + c4] = lo;
}

// -------- split-bf16 MFMA GEMM: C = A@B + bias (opt. exact GELU) --------
// A f32 [M][K] split on the fly; B pre-split bf16 planes BT{hi,lo}[N][K].
// Block = 4 waves (2x2), wave tile (MREP*16)x(NREP*16); BM=MREP*32, BN=NREP*32, BK=32.
template<int DOGELU, int MREP, int NREP>
__global__ __launch_bounds__(256) void gemm_mfma(const float* __restrict__ A,
    const unsigned short* __restrict__ BThi, const unsigned short* __restrict__ BTlo,
    const float* __restrict__ bias, float* __restrict__ C, int N, int K){
  constexpr int BM = MREP*32, BN = NREP*32;
  constexpr int APT = BM*32/256;   // f32 per thread (A tile)
  constexpr int BPT = BN*32/256;   // ushorts per thread per plane (B tile)
  __shared__ __align__(16) unsigned short smem[(2*BM + 2*BN)*32];
  unsigned short* sAhi = smem;
  unsigned short* sAlo = smem + BM*32;
  unsigned short* sBhi = smem + 2*BM*32;
  unsigned short* sBlo = smem + 2*BM*32 + BN*32;
  const int t = threadIdx.x;
  const int bm = blockIdx.y*BM, bn = blockIdx.x*BN;
  const int lane = t & 63;
  const int wv = t >> 6;
  const int mbase = (wv>>1)*(MREP*16), nbase = (wv&1)*(NREP*16);
  const int lr = lane & 15, kg = lane >> 4;
  f32x4 acc[MREP][NREP];
  #pragma unroll
  for (int m = 0; m < MREP; m++)
    #pragma unroll
    for (int n = 0; n < NREP; n++) acc[m][n] = (f32x4){0.f,0.f,0.f,0.f};

  int arow, akb, brow, bkb;
  if constexpr (BM == 128){ arow = t>>1; akb = (t&1)*16; } else { arow = t>>2; akb = (t&3)*8; }
  if constexpr (BN == 128){ brow = t>>1; bkb = (t&1)*16; } else { brow = t>>2; bkb = (t&3)*8; }

  for (int k0 = 0; k0 < K; k0 += 32){
    float fa[APT];
    unsigned short fbh[BPT], fbl[BPT];
    const float* pA = &A[(size_t)(bm+arow)*K + k0 + akb];
    #pragma unroll
    for (int i = 0; i < APT/4; i++) *(float4*)&fa[i*4] = *(const float4*)&pA[i*4];
    const unsigned short* pBh = &BThi[(size_t)(bn+brow)*K + k0 + bkb];
    const unsigned short* pBl = &BTlo[(size_t)(bn+brow)*K + k0 + bkb];
    #pragma unroll
    for (int i = 0; i < BPT/8; i++){
      *(u16x8*)&fbh[i*8] = *(const u16x8*)&pBh[i*8];
      *(u16x8*)&fbl[i*8] = *(const u16x8*)&pBl[i*8];
    }
    __syncthreads();   // previous iteration's fragment reads done
    #pragma unroll
    for (int g = 0; g < APT/8; g++){
      u16x8 hi, lo;
      #pragma unroll
      for (int j = 0; j < 8; j++){
        float x = fa[g*8+j];
        unsigned short hh = f2bu(x);
        hi[j] = hh;
        lo[j] = f2bu(x - bu2f(hh));
      }
      int kgw = (akb>>3) + g;
      *(u16x8*)&sAhi[swz8(arow, kgw)] = hi;
      *(u16x8*)&sAlo[swz8(arow, kgw)] = lo;
    }
    #pragma unroll
    for (int g = 0; g < BPT/8; g++){
      int kgw = (bkb>>3) + g;
      *(u16x8*)&sBhi[swz8(brow, kgw)] = *(u16x8*)&fbh[g*8];
      *(u16x8*)&sBlo[swz8(brow, kgw)] = *(u16x8*)&fbl[g*8];
    }
    __syncthreads();   // tile ready
    bf16x8 ah[MREP], al[MREP], bh[NREP], bl[NREP];
    #pragma unroll
    for (int m = 0; m < MREP; m++){
      int o = swz8(mbase + m*16 + lr, kg);
      ah[m] = *(bf16x8*)&sAhi[o];
      al[m] = *(bf16x8*)&sAlo[o];
    }
    #pragma unroll
    for (int n = 0; n < NREP; n++){
      int o = swz8(nbase + n*16 + lr, kg);
      bh[n] = *(bf16x8*)&sBhi[o];
      bl[n] = *(bf16x8*)&sBlo[o];
    }
    #pragma unroll
    for (int m = 0; m < MREP; m++)
      #pragma unroll
      for (int n = 0; n < NREP; n++){
        acc[m][n] = __builtin_amdgcn_mfma_f32_16x16x32_bf16(ah[m], bh[n], acc[m][n], 0, 0, 0);
        acc[m][n] = __builtin_amdgcn_mfma_f32_16x16x32_bf16(al[m], bh[n], acc[m][n], 0, 0, 0);
        acc[m][n] = __builtin_amdgcn_mfma_f32_16x16x32_bf16(ah[m], bl[n], acc[m][n], 0, 0, 0);
      }
  }
  // epilogue: C/D layout col=lane&15, row=(lane>>4)*4+reg  [m89-verified]
  #pragma unroll
  for (int m = 0; m < MREP; m++)
    #pragma unroll
    for (int n = 0; n < NREP; n++){
      int col = bn + nbase + n*16 + lr;
      int row0 = bm + mbase + m*16 + kg*4;
      float bb = bias[col];
      #pragma unroll
      for (int j = 0; j < 4; j++){
        float o = acc[m][n][j] + bb;
        if (DOGELU) o = 0.5f*o*(1.f + erff(o*0.70710678118f));
        C[(size_t)(row0+j)*N + col] = o;
      }
    }
}

// ---------------- flash attention, f32, 2-way j-split, Q in registers ----------------
#define SWZ(row, grp) ((((grp) ^ (((row) >> 2) & 7)) << 2))

__global__ __launch_bounds__(256) void attn_f32(const float* __restrict__ qkv, const float* __restrict__ pp,
                                                float* __restrict__ opart, float* __restrict__ mbuf,
                                                float* __restrict__ lbuf){
  __shared__ float qs[64*64];
  __shared__ float ks[64*64];   // K tile, then reused for P
  __shared__ float vs[64*64];
  __shared__ float ppj[64];
  int h = blockIdx.y;
  int i0 = blockIdx.x * 64;
  int z = blockIdx.z;           // j-split
  int t = threadIdx.x;
  int r = t >> 4, c = t & 15;
  #pragma unroll
  for (int p = 0; p < 4; p++){
    int row = (t >> 4) + p*16;
    int kgq = t & 15;
    float4 q4 = *(const float4*)&qkv[(size_t)(i0+row)*2304 + h*64 + kgq*4];
    q4.x *= 0.125f; q4.y *= 0.125f; q4.z *= 0.125f; q4.w *= 0.125f;
    *(float4*)&qs[row*64 + SWZ(row, kgq)] = q4;
  }
  __syncthreads();
  float4 qreg[4][16];
  #pragma unroll
  for (int ii = 0; ii < 4; ii++)
    #pragma unroll
    for (int kgq = 0; kgq < 16; kgq++)
      qreg[ii][kgq] = *(const float4*)&qs[(r*4+ii)*64 + SWZ(r*4+ii, kgq)];

  float mrow[4], lrow[4], acc[4][4];
  #pragma unroll
  for (int ii = 0; ii < 4; ii++){
    mrow[ii] = -1e30f; lrow[ii] = 0.f;
    #pragma unroll
    for (int dd = 0; dd < 4; dd++) acc[ii][dd] = 0.f;
  }
  for (int j0 = z*(NN/2); j0 < (z+1)*(NN/2); j0 += 64){
    __syncthreads();   // prior tile's PV reads of ks/vs complete
    #pragma unroll
    for (int p = 0; p < 4; p++){
      int row = (t >> 4) + p*16;
      int kgq = t & 15;
      float4 k4 = *(const float4*)&qkv[(size_t)(j0+row)*2304 + 768  + h*64 + kgq*4];
      float4 v4 = *(const float4*)&qkv[(size_t)(j0+row)*2304 + 1536 + h*64 + kgq*4];
      *(float4*)&ks[row*64 + SWZ(row, kgq)] = k4;
      *(float4*)&vs[row*64 + SWZ(row, kgq)] = v4;
    }
    if (t < 64) ppj[t] = pp[(size_t)(j0+t)*12 + h];
    __syncthreads();
    float s[4][4];
    #pragma unroll
    for (int ii=0;ii<4;ii++)
      #pragma unroll
      for (int jj=0;jj<4;jj++) s[ii][jj]=0.f;
    #pragma unroll
    for (int kgq = 0; kgq < 16; kgq++){
      float4 b4[4];
      #pragma unroll
      for (int jj = 0; jj < 4; jj++) b4[jj] = *(const float4*)&ks[(c*4+jj)*64 + SWZ(c*4+jj, kgq)];
      #pragma unroll
      for (int ii = 0; ii < 4; ii++){
        float4 a4 = qreg[ii][kgq];
        #pragma unroll
        for (int jj = 0; jj < 4; jj++)
          s[ii][jj] += a4.x*b4[jj].x + a4.y*b4[jj].y + a4.z*b4[jj].z + a4.w*b4[jj].w;
      }
    }
    float mx[4];
    #pragma unroll
    for (int ii = 0; ii < 4; ii++){
      s[ii][0]+=ppj[c*4+0]; s[ii][1]+=ppj[c*4+1]; s[ii][2]+=ppj[c*4+2]; s[ii][3]+=ppj[c*4+3];
      mx[ii] = fmaxf(fmaxf(s[ii][0],s[ii][1]), fmaxf(s[ii][2],s[ii][3]));
    }
    #pragma unroll
    for (int w = 1; w < 16; w <<= 1){
      #pragma unroll
      for (int ii = 0; ii < 4; ii++) mx[ii] = fmaxf(mx[ii], __shfl_xor(mx[ii], w, 64));
    }
    float al[4], rs[4];
    #pragma unroll
    for (int ii = 0; ii < 4; ii++){
      float mn = fmaxf(mrow[ii], mx[ii]);
      al[ii] = expf(mrow[ii] - mn);
      mrow[ii] = mn;
      float ssum = 0.f;
      #pragma unroll
      for (int jj = 0; jj < 4; jj++){ s[ii][jj] = expf(s[ii][jj] - mn); ssum += s[ii][jj]; }
      rs[ii] = ssum;
    }
    #pragma unroll
    for (int w = 1; w < 16; w <<= 1){
      #pragma unroll
      for (int ii = 0; ii < 4; ii++) rs[ii] += __shfl_xor(rs[ii], w, 64);
    }
    #pragma unroll
    for (int ii = 0; ii < 4; ii++){
      lrow[ii] = lrow[ii]*al[ii] + rs[ii];
      #pragma unroll
      for (int dd = 0; dd < 4; dd++) acc[ii][dd] *= al[ii];
    }
    __syncthreads();  // score-phase reads of ks done before P overwrite
    #pragma unroll
    for (int ii=0;ii<4;ii++)
      #pragma unroll
      for (int jj=0;jj<4;jj++) ks[(r*4+ii)*64 + SWZ(r*4+ii, c) + jj] = s[ii][jj];
    __syncthreads();
    #pragma unroll 4
    for (int jg = 0; jg < 16; jg++){
      float4 p4[4], v40, v41, v42, v43;
      #pragma unroll
      for (int ii = 0; ii < 4; ii++) p4[ii] = *(const float4*)&ks[(r*4+ii)*64 + SWZ(r*4+ii, jg)];
      v40 = *(const float4*)&vs[(jg*4+0)*64 + SWZ(jg*4+0, c)];
      v41 = *(const float4*)&vs[(jg*4+1)*64 + SWZ(jg*4+1, c)];
      v42 = *(const float4*)&vs[(jg*4+2)*64 + SWZ(jg*4+2, c)];
      v43 = *(const float4*)&vs[(jg*4+3)*64 + SWZ(jg*4+3, c)];
      #pragma unroll
      for (int ii = 0; ii < 4; ii++){
        acc[ii][0] += p4[ii].x*v40.x + p4[ii].y*v41.x + p4[ii].z*v42.x + p4[ii].w*v43.x;
        acc[ii][1] += p4[ii].x*v40.y + p4[ii].y*v41.y + p4[ii].z*v42.y + p4[ii].w*v43.y;
        acc[ii][2] += p4[ii].x*v40.z + p4[ii].y*v41.z + p4[ii].z*v42.z + p4[ii].w*v43.z;
        acc[ii][3] += p4[ii].x*v40.w + p4[ii].y*v41.w + p4[ii].z*v42.w + p4[ii].w*v43.w;
      }
    }
  }
  #pragma unroll
  for (int ii = 0; ii < 4; ii++){
    int row = i0 + r*4 + ii;
    size_t oidx = (((size_t)z*NN + row)*12 + h)*64 + c*4;
    float4 o = {acc[ii][0], acc[ii][1], acc[ii][2], acc[ii][3]};
    *(float4*)&opart[oidx] = o;
    if (c == 0){
      mbuf[((size_t)z*NN + row)*12 + h] = mrow[ii];
      lbuf[((size_t)z*NN + row)*12 + h] = lrow[ii];
    }
  }
}

__global__ __launch_bounds__(256) void attn_merge(const float* __restrict__ opart, const float* __restrict__ mbuf,
                                                  const float* __restrict__ lbuf, float* __restrict__ outp){
  int idx = blockIdx.x*256 + threadIdx.x;   // over NN*12*64
  int ih = idx >> 6;
  float m0 = mbuf[ih], m1 = mbuf[NN*12 + ih];
  float l0 = lbuf[ih], l1 = lbuf[NN*12 + ih];
  float mm = fmaxf(m0, m1);
  float e0 = expf(m0 - mm), e1 = expf(m1 - mm);
  float L = l0*e0 + l1*e1;
  outp[idx] = (opart[idx]*e0 + opart[(size_t)NN*12*64 + idx]*e1) / L;
}

// ---------------- residual add + LayerNorm ----------------
__global__ __launch_bounds__(256) void add_ln(const float* __restrict__ X, const float* __restrict__ R,
                                              const float* __restrict__ g, const float* __restrict__ b,
                                              float* __restrict__ Y){
  __shared__ float sbuf[4];
  int i = blockIdx.x, t = threadIdx.x;
  float x0 = X[(size_t)i*768 + t]       + R[(size_t)i*768 + t];
  float x1 = X[(size_t)i*768 + t + 256] + R[(size_t)i*768 + t + 256];
  float x2 = X[(size_t)i*768 + t + 512] + R[(size_t)i*768 + t + 512];
  float s = x0 + x1 + x2;
  for (int w = 32; w >= 1; w >>= 1) s += __shfl_xor(s, w, 64);
  if ((t & 63) == 0) sbuf[t >> 6] = s;
  __syncthreads();
  s = sbuf[0] + sbuf[1] + sbuf[2] + sbuf[3];
  float mean = s * (1.0f/768.0f);
  float d0 = x0-mean, d1 = x1-mean, d2 = x2-mean;
  float vv = d0*d0 + d1*d1 + d2*d2;
  __syncthreads();
  for (int w = 32; w >= 1; w >>= 1) vv += __shfl_xor(vv, w, 64);
  if ((t & 63) == 0) sbuf[t >> 6] = vv;
  __syncthreads();
  vv = sbuf[0] + sbuf[1] + sbuf[2] + sbuf[3];
  float inv = 1.0f / sqrtf(vv*(1.0f/768.0f) + 1e-5f);
  Y[(size_t)i*768 + t]       = d0*inv*g[t]     + b[t];
  Y[(size_t)i*768 + t + 256] = d1*inv*g[t+256] + b[t+256];
  Y[(size_t)i*768 + t + 512] = d2*inv*g[t+512] + b[t+512];
}

// ---------------- launcher ----------------
extern "C" void kernel_launch(void* const* d_in, const int* in_sizes, int n_in,
                              void* d_out, int out_size, void* d_ws, size_t ws_size,
                              hipStream_t stream) {
  const float* nf     = (const float*)d_in[0];
  const int*   ei     = (const int*)  d_in[1];
  const float* W_rwpe = (const float*)d_in[2];
  const float* b_rwpe = (const float*)d_in[3];
  const float* Wqkv   = (const float*)d_in[4];
  const float* bqkv   = (const float*)d_in[5];
  const float* Wpe    = (const float*)d_in[6];
  const float* bpe    = (const float*)d_in[7];
  const float* Wout   = (const float*)d_in[8];
  const float* bout   = (const float*)d_in[9];
  const float* W1     = (const float*)d_in[10];
  const float* b1     = (const float*)d_in[11];
  const float* W2     = (const float*)d_in[12];
  const float* b2     = (const float*)d_in[13];
  const float* g1     = (const float*)d_in[14];
  const float* be1    = (const float*)d_in[15];
  const float* g2     = (const float*)d_in[16];
  const float* be2    = (const float*)d_in[17];
  float* out = (float*)d_out;
  (void)in_sizes; (void)n_in; (void)out_size; (void)ws_size;

  char* base = (char*)d_ws;
  size_t off = 0;
  auto alloc = [&](size_t bytes){ void* p = base + off; off += (bytes + 255) & ~(size_t)255; return p; };

  const size_t PL = 7077888ULL;             // split-weight elems per layer
  const size_t oQ = 0, oO = 1769472ULL, oW1 = 2359296ULL, oW2 = 4718592ULL;
  unsigned short* whi = (unsigned short*)alloc(3*PL*2);
  unsigned short* wlo = (unsigned short*)alloc(3*PL*2);
  float* rw  = (float*)alloc((size_t)NN*8*4);
  float* pe  = (float*)alloc((size_t)NN*16*4);
  float* pp  = (float*)alloc((size_t)3*NN*12*4);
  char*  U   = (char*)alloc(93000000ULL);   // union region (phase1 graph | phase2 activations)

  // phase1 views
  float* P0   = (float*)U;
  float* P1   = P0 + (size_t)NN*NN;
  float* cscv = P1 + (size_t)NN*NN;
  int*   cscm = (int*)(cscv + (size_t)NN*CAP);
  int*   cnt  = (int*)(cscm + (size_t)NN*CAP);
  // phase2 views (aliases U; P0/P1 dead by then)
  float* qkvb  = (float*)U;
  float* attnb = qkvb  + (size_t)NN*2304;
  float* projb = attnb + (size_t)NN*768;
  float* h1    = projb + (size_t)NN*768;
  float* ffn1  = h1    + (size_t)NN*768;
  float* ffn2  = ffn1  + (size_t)NN*3072;
  float* hb    = ffn2  + (size_t)NN*768;
  float* opart = hb    + (size_t)NN*768;
  float* mbuf  = opart + (size_t)2*NN*12*64;
  float* lbuf  = mbuf  + (size_t)2*NN*12;

  // --- weight pre-split (independent of everything else) ---
  for (int l = 0; l < 3; l++){
    wconv<<<dim3(2304/32, 768/32), 256, 0, stream>>>(Wqkv + (size_t)l*768*2304, whi + l*PL + oQ,  wlo + l*PL + oQ,  768, 2304);
    wconv<<<dim3(768/32,  768/32), 256, 0, stream>>>(Wout + (size_t)l*768*768,  whi + l*PL + oO,  wlo + l*PL + oO,  768, 768);
    wconv<<<dim3(3072/32, 768/32), 256, 0, stream>>>(W1   + (size_t)l*768*3072, whi + l*PL + oW1, wlo + l*PL + oW1, 768, 3072);
    wconv<<<dim3(768/32, 3072/32), 256, 0, stream>>>(W2   + (size_t)l*3072*768, whi + l*PL + oW2, wlo + l*PL + oW2, 3072, 768);
  }

  // --- RW positional encoding ---
  hipMemsetAsync(P0, 0, (size_t)NN*NN*4, stream);
  scatter_edges<<<EE/256, 256, 0, stream>>>(ei, P0);
  row_norm<<<NN, 256, 0, stream>>>(P0, rw);
  build_csc<<<NN, 256, 0, stream>>>(P0, cscv, cscm, cnt);
  for (int k = 1; k < 8; k++){
    const float* src = (k & 1) ? P0 : P1;
    float*       dst = (k & 1) ? P1 : P0;
    spmm4<<<NN/4, 256, 0, stream>>>(src, cscv, cscm, cnt, dst, rw, k);
  }
  pe_kernel<<<NN*16/256, 256, 0, stream>>>(rw, W_rwpe, b_rwpe, pe);
  pp_kernel<<<3*NN*12/256, 256, 0, stream>>>(pe, Wpe, bpe, pp);

  // --- transformer layers ---
  const float* h = nf;
  for (int l = 0; l < 3; l++){
    gemm_mfma<0,4,4><<<dim3(2304/128, 2048/128), 256, 0, stream>>>(h, whi + l*PL + oQ, wlo + l*PL + oQ, bqkv + (size_t)l*2304, qkvb, 2304, 768);
    attn_f32<<<dim3(NN/64, 12, 2), 256, 0, stream>>>(qkvb, pp + (size_t)l*NN*12, opart, mbuf, lbuf);
    attn_merge<<<NN*12*64/256, 256, 0, stream>>>(opart, mbuf, lbuf, attnb);
    gemm_mfma<0,2,2><<<dim3(768/64, 2048/64), 256, 0, stream>>>(attnb, whi + l*PL + oO, wlo + l*PL + oO, bout + (size_t)l*768, projb, 768, 768);
    add_ln<<<NN, 256, 0, stream>>>(projb, h, g1 + (size_t)l*768, be1 + (size_t)l*768, h1);
    gemm_mfma<1,4,4><<<dim3(3072/128, 2048/128), 256, 0, stream>>>(h1, whi + l*PL + oW1, wlo + l*PL + oW1, b1 + (size_t)l*3072, ffn1, 3072, 768);
    gemm_mfma<0,2,2><<<dim3(768/64, 2048/64), 256, 0, stream>>>(ffn1, whi + l*PL + oW2, wlo + l*PL + oW2, b2 + (size_t)l*768, ffn2, 768, 3072);
    float* hout = (l == 2) ? out : hb;
    add_ln<<<NN, 256, 0, stream>>>(ffn2, h1, g2 + (size_t)l*768, be2 + (size_t)l*768, hout);
    h = hout;
  }
}

// Round 4
// 1473.041 us; speedup vs baseline: 2.5127x; 1.6812x over previous
//
#include <hip/hip_runtime.h>
#include <math.h>

#define NN 2048
#define EE 32768
#define CAP 256

typedef __attribute__((ext_vector_type(8))) short bf16x8;
typedef __attribute__((ext_vector_type(4))) float f32x4;
typedef __attribute__((ext_vector_type(8))) unsigned short u16x8;
typedef __attribute__((ext_vector_type(4))) unsigned short u16x4;

__device__ inline unsigned short f2bu(float x){
  unsigned u = __builtin_bit_cast(unsigned, x);
  return (unsigned short)((u + 0x7fffu + ((u>>16)&1u)) >> 16);
}
__device__ inline float bu2f(unsigned short h){
  unsigned u = ((unsigned)h) << 16;
  return __builtin_bit_cast(float, u);
}
// LDS ushort offset for (row, kgroup-of-8) tiles with 32-k rows (GEMM staging)
__device__ inline int swz8(int row, int kg){ return row*32 + ((kg ^ ((row>>1)&3))<<3); }
// LDS ushort offset for (row, kgroup-of-8) tiles with 64-k rows (attention)
__device__ inline int swzA(int row, int kg){ return row*64 + ((kg ^ (row&7))<<3); }

// ---------------- RW-PE graph kernels ----------------

__global__ __launch_bounds__(256) void scatter_edges(const int* __restrict__ ei, float* __restrict__ A){
  int e = blockIdx.x*256 + threadIdx.x;
  if (e >= EE) return;
  int s = ei[e], t = ei[EE + e];
  atomicAdd(&A[(size_t)s*NN + t], 1.0f);
  atomicAdd(&A[(size_t)t*NN + s], 1.0f);
}

__global__ __launch_bounds__(256) void row_norm(float* __restrict__ A, float* __restrict__ rw){
  __shared__ float sbuf[4];
  int i = blockIdx.x, t = threadIdx.x;
  float s = 0.f;
  for (int m = t; m < NN; m += 256) s += A[(size_t)i*NN + m];
  for (int w = 32; w >= 1; w >>= 1) s += __shfl_xor(s, w, 64);
  if ((t & 63) == 0) sbuf[t >> 6] = s;
  __syncthreads();
  s = sbuf[0] + sbuf[1] + sbuf[2] + sbuf[3];
  float inv = 1.0f / fmaxf(s, 1.0f);
  for (int m = t; m < NN; m += 256){
    float v = A[(size_t)i*NN + m] * inv;
    A[(size_t)i*NN + m] = v;
    if (m == i) rw[i*8 + 0] = v;
  }
}

__global__ __launch_bounds__(256) void build_csc(const float* __restrict__ T, float* __restrict__ cscv,
                                                 int* __restrict__ cscm, int* __restrict__ cnt){
  __shared__ int scnt;
  int j = blockIdx.x, t = threadIdx.x;
  if (t == 0) scnt = 0;
  __syncthreads();
  for (int m = t; m < NN; m += 256){
    float tv = T[(size_t)j*NN + m];
    if (tv != 0.f){
      int p = atomicAdd(&scnt, 1);
      if (p < CAP){
        cscm[j*CAP + p] = m;
        cscv[j*CAP + p] = T[(size_t)m*NN + j];
      }
    }
  }
  __syncthreads();
  if (t == 0) cnt[j] = min(scnt, CAP);
}

__global__ __launch_bounds__(256) void spmm4(const float* __restrict__ Tk, const float* __restrict__ cscv,
                                             const int* __restrict__ cscm, const int* __restrict__ cnt,
                                             float* __restrict__ Tn, float* __restrict__ rw, int kidx){
  __shared__ float tk[4][NN + 4];
  int i0 = blockIdx.x*4, t = threadIdx.x;
  for (int r = 0; r < 4; r++){
    for (int m4 = t; m4 < NN/4; m4 += 256){
      float4 v = *(const float4*)&Tk[(size_t)(i0+r)*NN + m4*4];
      tk[r][m4*4+0] = v.x; tk[r][m4*4+1] = v.y; tk[r][m4*4+2] = v.z; tk[r][m4*4+3] = v.w;
    }
  }
  __syncthreads();
  for (int j = t; j < NN; j += 256){
    int n = cnt[j];
    const int*   im = &cscm[j*CAP];
    const float* iv = &cscv[j*CAP];
    float a0=0.f,a1=0.f,a2=0.f,a3=0.f;
    for (int c = 0; c < n; c++){
      int m = im[c]; float v = iv[c];
      a0 += v*tk[0][m]; a1 += v*tk[1][m]; a2 += v*tk[2][m]; a3 += v*tk[3][m];
    }
    Tn[(size_t)(i0+0)*NN + j] = a0;
    Tn[(size_t)(i0+1)*NN + j] = a1;
    Tn[(size_t)(i0+2)*NN + j] = a2;
    Tn[(size_t)(i0+3)*NN + j] = a3;
    if (j == i0+0) rw[j*8 + kidx] = a0;
    if (j == i0+1) rw[j*8 + kidx] = a1;
    if (j == i0+2) rw[j*8 + kidx] = a2;
    if (j == i0+3) rw[j*8 + kidx] = a3;
  }
}

__global__ __launch_bounds__(256) void pe_kernel(const float* __restrict__ rw, const float* __restrict__ W,
                                                 const float* __restrict__ b, float* __restrict__ pe){
  int idx = blockIdx.x*256 + threadIdx.x;
  if (idx >= NN*16) return;
  int i = idx >> 4, c = idx & 15;
  float acc = b[c];
  #pragma unroll
  for (int k = 0; k < 8; k++) acc += rw[i*8+k] * W[k*16+c];
  pe[idx] = acc;
}

__global__ __launch_bounds__(256) void pp_kernel(const float* __restrict__ pe, const float* __restrict__ Wpe,
                                                 const float* __restrict__ bpe, float* __restrict__ pp){
  int idx = blockIdx.x*256 + threadIdx.x;
  if (idx >= 3*NN*12) return;
  int l = idx / (NN*12);
  int rm = idx % (NN*12);
  int j = rm / 12, h = rm % 12;
  float acc = bpe[l*12 + h];
  #pragma unroll
  for (int c = 0; c < 16; c++) acc += pe[j*16+c] * Wpe[(l*16+c)*12 + h];
  pp[idx] = acc;
}

// -------- weight transpose + split-bf16 convert: W[K][N] -> T{hi,lo}[N][K] --------
__global__ __launch_bounds__(256) void wconv(const float* __restrict__ W, unsigned short* __restrict__ Thi,
                                             unsigned short* __restrict__ Tlo, int K, int N){
  __shared__ float ld[32*33];
  int k0 = blockIdx.y*32, n0 = blockIdx.x*32;
  int t = threadIdx.x;
  int r = t>>3, c4 = (t&7)*4;
  float4 v = *(const float4*)&W[(size_t)(k0+r)*N + n0 + c4];
  ld[(c4+0)*33 + r] = v.x; ld[(c4+1)*33 + r] = v.y; ld[(c4+2)*33 + r] = v.z; ld[(c4+3)*33 + r] = v.w;
  __syncthreads();
  u16x4 hi, lo;
  #pragma unroll
  for (int i = 0; i < 4; i++){
    float x = ld[r*33 + c4 + i];
    unsigned short hh = f2bu(x);
    hi[i] = hh;
    lo[i] = f2bu(x - bu2f(hh));
  }
  *(u16x4*)&Thi[(size_t)(n0+r)*K + k0 + c4] = hi;
  *(u16x4*)&Tlo[(size_t)(n0+r)*K + k0 + c4] = lo;
}

// -------- split-bf16 MFMA GEMM: C = A@B + bias (opt. exact GELU) --------
template<int DOGELU, int MREP, int NREP>
__global__ __launch_bounds__(256) void gemm_mfma(const float* __restrict__ A,
    const unsigned short* __restrict__ BThi, const unsigned short* __restrict__ BTlo,
    const float* __restrict__ bias, float* __restrict__ C, int N, int K){
  constexpr int BM = MREP*32, BN = NREP*32;
  constexpr int APT = BM*32/256;
  constexpr int BPT = BN*32/256;
  __shared__ __align__(16) unsigned short smem[(2*BM + 2*BN)*32];
  unsigned short* sAhi = smem;
  unsigned short* sAlo = smem + BM*32;
  unsigned short* sBhi = smem + 2*BM*32;
  unsigned short* sBlo = smem + 2*BM*32 + BN*32;
  const int t = threadIdx.x;
  const int bm = blockIdx.y*BM, bn = blockIdx.x*BN;
  const int lane = t & 63;
  const int wv = t >> 6;
  const int mbase = (wv>>1)*(MREP*16), nbase = (wv&1)*(NREP*16);
  const int lr = lane & 15, kg = lane >> 4;
  f32x4 acc[MREP][NREP];
  #pragma unroll
  for (int m = 0; m < MREP; m++)
    #pragma unroll
    for (int n = 0; n < NREP; n++) acc[m][n] = (f32x4){0.f,0.f,0.f,0.f};

  int arow, akb, brow, bkb;
  if constexpr (BM == 128){ arow = t>>1; akb = (t&1)*16; } else { arow = t>>2; akb = (t&3)*8; }
  if constexpr (BN == 128){ brow = t>>1; bkb = (t&1)*16; } else { brow = t>>2; bkb = (t&3)*8; }

  for (int k0 = 0; k0 < K; k0 += 32){
    float fa[APT];
    unsigned short fbh[BPT], fbl[BPT];
    const float* pA = &A[(size_t)(bm+arow)*K + k0 + akb];
    #pragma unroll
    for (int i = 0; i < APT/4; i++) *(float4*)&fa[i*4] = *(const float4*)&pA[i*4];
    const unsigned short* pBh = &BThi[(size_t)(bn+brow)*K + k0 + bkb];
    const unsigned short* pBl = &BTlo[(size_t)(bn+brow)*K + k0 + bkb];
    #pragma unroll
    for (int i = 0; i < BPT/8; i++){
      *(u16x8*)&fbh[i*8] = *(const u16x8*)&pBh[i*8];
      *(u16x8*)&fbl[i*8] = *(const u16x8*)&pBl[i*8];
    }
    __syncthreads();
    #pragma unroll
    for (int g = 0; g < APT/8; g++){
      u16x8 hi, lo;
      #pragma unroll
      for (int j = 0; j < 8; j++){
        float x = fa[g*8+j];
        unsigned short hh = f2bu(x);
        hi[j] = hh;
        lo[j] = f2bu(x - bu2f(hh));
      }
      int kgw = (akb>>3) + g;
      *(u16x8*)&sAhi[swz8(arow, kgw)] = hi;
      *(u16x8*)&sAlo[swz8(arow, kgw)] = lo;
    }
    #pragma unroll
    for (int g = 0; g < BPT/8; g++){
      int kgw = (bkb>>3) + g;
      *(u16x8*)&sBhi[swz8(brow, kgw)] = *(u16x8*)&fbh[g*8];
      *(u16x8*)&sBlo[swz8(brow, kgw)] = *(u16x8*)&fbl[g*8];
    }
    __syncthreads();
    bf16x8 ah[MREP], al[MREP], bh[NREP], bl[NREP];
    #pragma unroll
    for (int m = 0; m < MREP; m++){
      int o = swz8(mbase + m*16 + lr, kg);
      ah[m] = *(bf16x8*)&sAhi[o];
      al[m] = *(bf16x8*)&sAlo[o];
    }
    #pragma unroll
    for (int n = 0; n < NREP; n++){
      int o = swz8(nbase + n*16 + lr, kg);
      bh[n] = *(bf16x8*)&sBhi[o];
      bl[n] = *(bf16x8*)&sBlo[o];
    }
    #pragma unroll
    for (int m = 0; m < MREP; m++)
      #pragma unroll
      for (int n = 0; n < NREP; n++){
        acc[m][n] = __builtin_amdgcn_mfma_f32_16x16x32_bf16(ah[m], bh[n], acc[m][n], 0, 0, 0);
        acc[m][n] = __builtin_amdgcn_mfma_f32_16x16x32_bf16(al[m], bh[n], acc[m][n], 0, 0, 0);
        acc[m][n] = __builtin_amdgcn_mfma_f32_16x16x32_bf16(ah[m], bl[n], acc[m][n], 0, 0, 0);
      }
  }
  #pragma unroll
  for (int m = 0; m < MREP; m++)
    #pragma unroll
    for (int n = 0; n < NREP; n++){
      int col = bn + nbase + n*16 + lr;
      int row0 = bm + mbase + m*16 + kg*4;
      float bb = bias[col];
      #pragma unroll
      for (int j = 0; j < 4; j++){
        float o = acc[m][n][j] + bb;
        if (DOGELU) o = 0.5f*o*(1.f + erff(o*0.70710678118f));
        C[(size_t)(row0+j)*N + col] = o;
      }
    }
}

// -------- qkv -> per-head split-bf16 planes; V transposed to [h][d][j] --------
__global__ __launch_bounds__(256) void qkv_planes(const float* __restrict__ qkv,
    unsigned short* __restrict__ qhi, unsigned short* __restrict__ qlo,
    unsigned short* __restrict__ khi, unsigned short* __restrict__ klo,
    unsigned short* __restrict__ vthi, unsigned short* __restrict__ vtlo){
  __shared__ float vb[64*69];
  const int h = blockIdx.y, j0 = blockIdx.x*64;
  const int t = threadIdx.x;
  const int jl = t >> 4, d4 = (t & 15)*4;
  #pragma unroll
  for (int p = 0; p < 4; p++){
    int j = jl + p*16;
    const float* row = &qkv[(size_t)(j0 + j)*2304 + h*64 + d4];
    float4 q4 = *(const float4*)&row[0];
    float4 k4 = *(const float4*)&row[768];
    float4 v4 = *(const float4*)&row[1536];
    float qv[4] = {q4.x*0.125f, q4.y*0.125f, q4.z*0.125f, q4.w*0.125f};
    float kv[4] = {k4.x, k4.y, k4.z, k4.w};
    float vv[4] = {v4.x, v4.y, v4.z, v4.w};
    u16x4 qh_, ql_, kh_, kl_;
    #pragma unroll
    for (int i = 0; i < 4; i++){
      unsigned short hh = f2bu(qv[i]); qh_[i] = hh; ql_[i] = f2bu(qv[i] - bu2f(hh));
      hh = f2bu(kv[i]); kh_[i] = hh; kl_[i] = f2bu(kv[i] - bu2f(hh));
      vb[(d4+i)*0 + j*69 + d4 + i] = vv[i];
    }
    size_t ob = ((size_t)h*NN + j0 + j)*64 + d4;
    *(u16x4*)&qhi[ob] = qh_; *(u16x4*)&qlo[ob] = ql_;
    *(u16x4*)&khi[ob] = kh_; *(u16x4*)&klo[ob] = kl_;
  }
  __syncthreads();
  #pragma unroll
  for (int p = 0; p < 4; p++){
    int d = jl + p*16;
    u16x4 vh_, vl_;
    #pragma unroll
    for (int i = 0; i < 4; i++){
      float x = vb[(d4+i)*69 + d];
      unsigned short hh = f2bu(x);
      vh_[i] = hh; vl_[i] = f2bu(x - bu2f(hh));
    }
    size_t ob = ((size_t)h*64 + d)*NN + j0 + d4;
    *(u16x4*)&vthi[ob] = vh_;
    *(u16x4*)&vtlo[ob] = vl_;
  }
}

// ---------------- MFMA flash attention: S^T = K Q^T, O^T = V^T P^T ----------------
// grid (32 qblocks, 12 heads, 2 j-splits), 256 thr (4 waves x 16-q strips).
__global__ __launch_bounds__(256) void attn_mfma(
    const unsigned short* __restrict__ qhi, const unsigned short* __restrict__ qlo,
    const unsigned short* __restrict__ khi, const unsigned short* __restrict__ klo,
    const unsigned short* __restrict__ vthi, const unsigned short* __restrict__ vtlo,
    const float* __restrict__ pp, float* __restrict__ opart,
    float* __restrict__ mbuf, float* __restrict__ lbuf){
  __shared__ __align__(16) unsigned short sKhi[64*64], sKlo[64*64];
  __shared__ __align__(16) unsigned short sVhi[64*64], sVlo[64*64];
  __shared__ __align__(16) unsigned short sPhi[64*64], sPlo[64*64];
  __shared__ float ppj[64];
  const int h = blockIdx.y, i0 = blockIdx.x*64, z = blockIdx.z;
  const int t = threadIdx.x, l = t & 63, w = t >> 6;
  const int lr = l & 15, lg = l >> 4;
  const int q0w = w*16;
  const int qrow = i0 + q0w + lr;
  // Q fragments (B-operand: rows of Q, 8 contiguous d per lane)
  bf16x8 qh[2], ql[2];
  #pragma unroll
  for (int ks = 0; ks < 2; ks++){
    size_t qo = ((size_t)h*NN + qrow)*64 + (ks*4 + lg)*8;
    qh[ks] = *(const bf16x8*)&qhi[qo];
    ql[ks] = *(const bf16x8*)&qlo[qo];
  }
  float mrow = -1e30f, lrow = 0.f;
  f32x4 oacc[4];
  #pragma unroll
  for (int dt = 0; dt < 4; dt++) oacc[dt] = (f32x4){0.f,0.f,0.f,0.f};

  for (int jt = 0; jt < 16; jt++){
    const int jb = z*(NN/2) + jt*64;
    __syncthreads();   // previous iteration's K/V reads complete
    {
      size_t kb = ((size_t)h*NN + jb + l)*64;
      size_t vbg = ((size_t)h*64 + l)*NN + jb;
      #pragma unroll
      for (int i = 0; i < 2; i++){
        int dg = w*2 + i;
        *(u16x8*)&sKhi[swzA(l, dg)] = *(const u16x8*)&khi[kb + dg*8];
        *(u16x8*)&sKlo[swzA(l, dg)] = *(const u16x8*)&klo[kb + dg*8];
        *(u16x8*)&sVhi[swzA(l, dg)] = *(const u16x8*)&vthi[vbg + dg*8];
        *(u16x8*)&sVlo[swzA(l, dg)] = *(const u16x8*)&vtlo[vbg + dg*8];
      }
      if (t < 64) ppj[t] = pp[(size_t)(jb + t)*12 + h];
    }
    __syncthreads();
    // ---- QK^T: S^T[j][q], 4 j-subtiles x 2 k-steps x 3 split products ----
    f32x4 sa[4];
    #pragma unroll
    for (int j4 = 0; j4 < 4; j4++) sa[j4] = (f32x4){0.f,0.f,0.f,0.f};
    #pragma unroll
    for (int j4 = 0; j4 < 4; j4++){
      #pragma unroll
      for (int ks = 0; ks < 2; ks++){
        int ro = j4*16 + lr, dg = ks*4 + lg;
        bf16x8 kh = *(const bf16x8*)&sKhi[swzA(ro, dg)];
        bf16x8 kl = *(const bf16x8*)&sKlo[swzA(ro, dg)];
        sa[j4] = __builtin_amdgcn_mfma_f32_16x16x32_bf16(kh, qh[ks], sa[j4], 0, 0, 0);
        sa[j4] = __builtin_amdgcn_mfma_f32_16x16x32_bf16(kl, qh[ks], sa[j4], 0, 0, 0);
        sa[j4] = __builtin_amdgcn_mfma_f32_16x16x32_bf16(kh, ql[ks], sa[j4], 0, 0, 0);
      }
    }
    // ---- bias + online softmax (lane owns one q; j in-lane + xor16/32) ----
    float mx = -1e30f;
    #pragma unroll
    for (int j4 = 0; j4 < 4; j4++)
      #pragma unroll
      for (int r = 0; r < 4; r++){
        sa[j4][r] += ppj[j4*16 + lg*4 + r];
        mx = fmaxf(mx, sa[j4][r]);
      }
    mx = fmaxf(mx, __shfl_xor(mx, 16, 64));
    mx = fmaxf(mx, __shfl_xor(mx, 32, 64));
    float mn = fmaxf(mrow, mx);
    float alq = expf(mrow - mn);
    mrow = mn;
    float rs = 0.f;
    #pragma unroll
    for (int j4 = 0; j4 < 4; j4++)
      #pragma unroll
      for (int r = 0; r < 4; r++){
        float pv = expf(sa[j4][r] - mn);
        sa[j4][r] = pv;
        rs += pv;
      }
    rs += __shfl_xor(rs, 16, 64);
    rs += __shfl_xor(rs, 32, 64);
    lrow = lrow*alq + rs;
    #pragma unroll
    for (int dt = 0; dt < 4; dt++)
      #pragma unroll
      for (int r = 0; r < 4; r++) oacc[dt][r] *= alq;
    // ---- P^T -> LDS (wave-private q rows; matches B-frag swizzle) ----
    #pragma unroll
    for (int j4 = 0; j4 < 4; j4++)
      #pragma unroll
      for (int r = 0; r < 4; r++){
        int j = j4*16 + lg*4 + r, q = q0w + lr;
        int o = q*64 + (((j>>3) ^ (q&7))<<3) + (j&7);
        float pv = sa[j4][r];
        unsigned short ph = f2bu(pv);
        sPhi[o] = ph;
        sPlo[o] = f2bu(pv - bu2f(ph));
      }
    // ---- PV: O^T[d][q] += V^T[d][j] P^T[j][q] ----
    #pragma unroll
    for (int ks = 0; ks < 2; ks++){
      int q = q0w + lr, dg = ks*4 + lg;
      bf16x8 pf = *(const bf16x8*)&sPhi[swzA(q, dg)];
      bf16x8 pl = *(const bf16x8*)&sPlo[swzA(q, dg)];
      #pragma unroll
      for (int dt = 0; dt < 4; dt++){
        int dr = dt*16 + lr;
        bf16x8 vh = *(const bf16x8*)&sVhi[swzA(dr, dg)];
        bf16x8 vl = *(const bf16x8*)&sVlo[swzA(dr, dg)];
        oacc[dt] = __builtin_amdgcn_mfma_f32_16x16x32_bf16(vh, pf, oacc[dt], 0, 0, 0);
        oacc[dt] = __builtin_amdgcn_mfma_f32_16x16x32_bf16(vh, pl, oacc[dt], 0, 0, 0);
        oacc[dt] = __builtin_amdgcn_mfma_f32_16x16x32_bf16(vl, pf, oacc[dt], 0, 0, 0);
      }
    }
  }
  // ---- epilogue: raw accumulator + stats (merged by attn_merge) ----
  #pragma unroll
  for (int dt = 0; dt < 4; dt++)
    #pragma unroll
    for (int r = 0; r < 4; r++){
      int d = dt*16 + lg*4 + r;
      opart[(((size_t)z*NN + qrow)*12 + h)*64 + d] = oacc[dt][r];
    }
  if (lg == 0){
    mbuf[((size_t)z*NN + qrow)*12 + h] = mrow;
    lbuf[((size_t)z*NN + qrow)*12 + h] = lrow;
  }
}

__global__ __launch_bounds__(256) void attn_merge(const float* __restrict__ opart, const float* __restrict__ mbuf,
                                                  const float* __restrict__ lbuf, float* __restrict__ outp){
  int idx = blockIdx.x*256 + threadIdx.x;   // over NN*12*64, layout [q][h][d]
  int ih = idx >> 6;
  int q = ih / 12, hh = ih % 12, d = idx & 63;
  float m0 = mbuf[ih], m1 = mbuf[NN*12 + ih];
  float l0 = lbuf[ih], l1 = lbuf[NN*12 + ih];
  float mm = fmaxf(m0, m1);
  float e0 = expf(m0 - mm), e1 = expf(m1 - mm);
  float L = l0*e0 + l1*e1;
  float o = (opart[idx]*e0 + opart[(size_t)NN*12*64 + idx]*e1) / L;
  outp[(size_t)q*768 + hh*64 + d] = o;
}

// ---------------- residual add + LayerNorm ----------------
__global__ __launch_bounds__(256) void add_ln(const float* __restrict__ X, const float* __restrict__ R,
                                              const float* __restrict__ g, const float* __restrict__ b,
                                              float* __restrict__ Y){
  __shared__ float sbuf[4];
  int i = blockIdx.x, t = threadIdx.x;
  float x0 = X[(size_t)i*768 + t]       + R[(size_t)i*768 + t];
  float x1 = X[(size_t)i*768 + t + 256] + R[(size_t)i*768 + t + 256];
  float x2 = X[(size_t)i*768 + t + 512] + R[(size_t)i*768 + t + 512];
  float s = x0 + x1 + x2;
  for (int w = 32; w >= 1; w >>= 1) s += __shfl_xor(s, w, 64);
  if ((t & 63) == 0) sbuf[t >> 6] = s;
  __syncthreads();
  s = sbuf[0] + sbuf[1] + sbuf[2] + sbuf[3];
  float mean = s * (1.0f/768.0f);
  float d0 = x0-mean, d1 = x1-mean, d2 = x2-mean;
  float vv = d0*d0 + d1*d1 + d2*d2;
  __syncthreads();
  for (int w = 32; w >= 1; w >>= 1) vv += __shfl_xor(vv, w, 64);
  if ((t & 63) == 0) sbuf[t >> 6] = vv;
  __syncthreads();
  vv = sbuf[0] + sbuf[1] + sbuf[2] + sbuf[3];
  float inv = 1.0f / sqrtf(vv*(1.0f/768.0f) + 1e-5f);
  Y[(size_t)i*768 + t]       = d0*inv*g[t]     + b[t];
  Y[(size_t)i*768 + t + 256] = d1*inv*g[t+256] + b[t+256];
  Y[(size_t)i*768 + t + 512] = d2*inv*g[t+512] + b[t+512];
}

// ---------------- launcher ----------------
extern "C" void kernel_launch(void* const* d_in, const int* in_sizes, int n_in,
                              void* d_out, int out_size, void* d_ws, size_t ws_size,
                              hipStream_t stream) {
  const float* nf     = (const float*)d_in[0];
  const int*   ei     = (const int*)  d_in[1];
  const float* W_rwpe = (const float*)d_in[2];
  const float* b_rwpe = (const float*)d_in[3];
  const float* Wqkv   = (const float*)d_in[4];
  const float* bqkv   = (const float*)d_in[5];
  const float* Wpe    = (const float*)d_in[6];
  const float* bpe    = (const float*)d_in[7];
  const float* Wout   = (const float*)d_in[8];
  const float* bout   = (const float*)d_in[9];
  const float* W1     = (const float*)d_in[10];
  const float* b1     = (const float*)d_in[11];
  const float* W2     = (const float*)d_in[12];
  const float* b2     = (const float*)d_in[13];
  const float* g1     = (const float*)d_in[14];
  const float* be1    = (const float*)d_in[15];
  const float* g2     = (const float*)d_in[16];
  const float* be2    = (const float*)d_in[17];
  float* out = (float*)d_out;
  (void)in_sizes; (void)n_in; (void)out_size; (void)ws_size;

  char* base = (char*)d_ws;
  size_t off = 0;
  auto alloc = [&](size_t bytes){ void* p = base + off; off += (bytes + 255) & ~(size_t)255; return p; };

  const size_t PL = 7077888ULL;             // split-weight elems per layer
  const size_t oQ = 0, oO = 1769472ULL, oW1 = 2359296ULL, oW2 = 4718592ULL;
  unsigned short* whi = (unsigned short*)alloc(3*PL*2);
  unsigned short* wlo = (unsigned short*)alloc(3*PL*2);
  float* rw  = (float*)alloc((size_t)NN*8*4);
  float* pe  = (float*)alloc((size_t)NN*16*4);
  float* pp  = (float*)alloc((size_t)3*NN*12*4);
  char*  U   = (char*)alloc(93000000ULL);   // union region (phase1 graph | phase2 activations)

  // phase1 views
  float* P0   = (float*)U;
  float* P1   = P0 + (size_t)NN*NN;
  float* cscv = P1 + (size_t)NN*NN;
  int*   cscm = (int*)(cscv + (size_t)NN*CAP);
  int*   cnt  = (int*)(cscm + (size_t)NN*CAP);
  // phase2 views (aliases U; P0/P1 dead by then)
  float* qkvb  = (float*)U;
  float* attnb = qkvb  + (size_t)NN*2304;
  float* projb = attnb + (size_t)NN*768;
  float* h1    = projb + (size_t)NN*768;
  float* ffn1  = h1    + (size_t)NN*768;
  float* ffn2  = ffn1  + (size_t)NN*3072;
  float* hb    = ffn2  + (size_t)NN*768;
  float* opart = hb    + (size_t)NN*768;
  float* mbuf  = opart + (size_t)2*NN*12*64;
  float* lbuf  = mbuf  + (size_t)2*NN*12;
  // attention bf16 planes alias ffn1 (dead during attention, 18.9MB <= 25.2MB)
  const size_t PS = (size_t)12*NN*64;       // 1572864 ushorts per plane
  unsigned short* qhi_p = (unsigned short*)ffn1;
  unsigned short* qlo_p = qhi_p + PS;
  unsigned short* khi_p = qhi_p + 2*PS;
  unsigned short* klo_p = qhi_p + 3*PS;
  unsigned short* vthi_p = qhi_p + 4*PS;
  unsigned short* vtlo_p = qhi_p + 5*PS;

  // --- weight pre-split ---
  for (int l = 0; l < 3; l++){
    wconv<<<dim3(2304/32, 768/32), 256, 0, stream>>>(Wqkv + (size_t)l*768*2304, whi + l*PL + oQ,  wlo + l*PL + oQ,  768, 2304);
    wconv<<<dim3(768/32,  768/32), 256, 0, stream>>>(Wout + (size_t)l*768*768,  whi + l*PL + oO,  wlo + l*PL + oO,  768, 768);
    wconv<<<dim3(3072/32, 768/32), 256, 0, stream>>>(W1   + (size_t)l*768*3072, whi + l*PL + oW1, wlo + l*PL + oW1, 768, 3072);
    wconv<<<dim3(768/32, 3072/32), 256, 0, stream>>>(W2   + (size_t)l*3072*768, whi + l*PL + oW2, wlo + l*PL + oW2, 3072, 768);
  }

  // --- RW positional encoding ---
  hipMemsetAsync(P0, 0, (size_t)NN*NN*4, stream);
  scatter_edges<<<EE/256, 256, 0, stream>>>(ei, P0);
  row_norm<<<NN, 256, 0, stream>>>(P0, rw);
  build_csc<<<NN, 256, 0, stream>>>(P0, cscv, cscm, cnt);
  for (int k = 1; k < 8; k++){
    const float* src = (k & 1) ? P0 : P1;
    float*       dst = (k & 1) ? P1 : P0;
    spmm4<<<NN/4, 256, 0, stream>>>(src, cscv, cscm, cnt, dst, rw, k);
  }
  pe_kernel<<<NN*16/256, 256, 0, stream>>>(rw, W_rwpe, b_rwpe, pe);
  pp_kernel<<<3*NN*12/256, 256, 0, stream>>>(pe, Wpe, bpe, pp);

  // --- transformer layers ---
  const float* h = nf;
  for (int l = 0; l < 3; l++){
    gemm_mfma<0,4,4><<<dim3(2304/128, 2048/128), 256, 0, stream>>>(h, whi + l*PL + oQ, wlo + l*PL + oQ, bqkv + (size_t)l*2304, qkvb, 2304, 768);
    qkv_planes<<<dim3(NN/64, 12), 256, 0, stream>>>(qkvb, qhi_p, qlo_p, khi_p, klo_p, vthi_p, vtlo_p);
    attn_mfma<<<dim3(NN/64, 12, 2), 256, 0, stream>>>(qhi_p, qlo_p, khi_p, klo_p, vthi_p, vtlo_p,
                                                      pp + (size_t)l*NN*12, opart, mbuf, lbuf);
    attn_merge<<<NN*12*64/256, 256, 0, stream>>>(opart, mbuf, lbuf, attnb);
    gemm_mfma<0,2,2><<<dim3(768/64, 2048/64), 256, 0, stream>>>(attnb, whi + l*PL + oO, wlo + l*PL + oO, bout + (size_t)l*768, projb, 768, 768);
    add_ln<<<NN, 256, 0, stream>>>(projb, h, g1 + (size_t)l*768, be1 + (size_t)l*768, h1);
    gemm_mfma<1,4,4><<<dim3(3072/128, 2048/128), 256, 0, stream>>>(h1, whi + l*PL + oW1, wlo + l*PL + oW1, b1 + (size_t)l*3072, ffn1, 3072, 768);
    gemm_mfma<0,2,2><<<dim3(768/64, 2048/64), 256, 0, stream>>>(ffn1, whi + l*PL + oW2, wlo + l*PL + oW2, b2 + (size_t)l*768, ffn2, 768, 3072);
    float* hout = (l == 2) ? out : hb;
    add_ln<<<NN, 256, 0, stream>>>(ffn2, h1, g2 + (size_t)l*768, be2 + (size_t)l*768, hout);
    h = hout;
  }
}

// Round 5
// 1400.005 us; speedup vs baseline: 2.6438x; 1.0522x over previous
//
#include <hip/hip_runtime.h>
#include <math.h>

#define NN 2048
#define EE 32768
#define CAP 256
#define LOG2E 1.4426950408889634f

typedef __attribute__((ext_vector_type(8))) short bf16x8;
typedef __attribute__((ext_vector_type(4))) float f32x4;
typedef __attribute__((ext_vector_type(8))) unsigned short u16x8;
typedef __attribute__((ext_vector_type(4))) unsigned short u16x4;

__device__ inline unsigned short f2bu(float x){
  unsigned u = __builtin_bit_cast(unsigned, x);
  return (unsigned short)((u + 0x7fffu + ((u>>16)&1u)) >> 16);
}
__device__ inline float bu2f(unsigned short h){
  unsigned u = ((unsigned)h) << 16;
  return __builtin_bit_cast(float, u);
}
__device__ inline int swz8(int row, int kg){ return row*32 + ((kg ^ ((row>>1)&3))<<3); }
__device__ inline int swzA(int row, int kg){ return row*64 + ((kg ^ (row&7))<<3); }

// ---------------- RW-PE graph kernels ----------------

__global__ __launch_bounds__(256) void scatter_edges(const int* __restrict__ ei, float* __restrict__ A){
  int e = blockIdx.x*256 + threadIdx.x;
  if (e >= EE) return;
  int s = ei[e], t = ei[EE + e];
  atomicAdd(&A[(size_t)s*NN + t], 1.0f);
  atomicAdd(&A[(size_t)t*NN + s], 1.0f);
}

__global__ __launch_bounds__(256) void row_norm(float* __restrict__ A, float* __restrict__ rw){
  __shared__ float sbuf[4];
  int i = blockIdx.x, t = threadIdx.x;
  float s = 0.f;
  for (int m = t; m < NN; m += 256) s += A[(size_t)i*NN + m];
  for (int w = 32; w >= 1; w >>= 1) s += __shfl_xor(s, w, 64);
  if ((t & 63) == 0) sbuf[t >> 6] = s;
  __syncthreads();
  s = sbuf[0] + sbuf[1] + sbuf[2] + sbuf[3];
  float inv = 1.0f / fmaxf(s, 1.0f);
  for (int m = t; m < NN; m += 256){
    float v = A[(size_t)i*NN + m] * inv;
    A[(size_t)i*NN + m] = v;
    if (m == i) rw[i*8 + 0] = v;
  }
}

__global__ __launch_bounds__(256) void build_csc(const float* __restrict__ T, float* __restrict__ cscv,
                                                 int* __restrict__ cscm, int* __restrict__ cnt){
  __shared__ int scnt;
  int j = blockIdx.x, t = threadIdx.x;
  if (t == 0) scnt = 0;
  __syncthreads();
  for (int m = t; m < NN; m += 256){
    float tv = T[(size_t)j*NN + m];
    if (tv != 0.f){
      int p = atomicAdd(&scnt, 1);
      if (p < CAP){
        cscm[j*CAP + p] = m;
        cscv[j*CAP + p] = T[(size_t)m*NN + j];
      }
    }
  }
  __syncthreads();
  if (t == 0) cnt[j] = min(scnt, CAP);
}

__global__ __launch_bounds__(256) void spmm4(const float* __restrict__ Tk, const float* __restrict__ cscv,
                                             const int* __restrict__ cscm, const int* __restrict__ cnt,
                                             float* __restrict__ Tn, float* __restrict__ rw, int kidx){
  __shared__ float tk[4][NN + 4];
  int i0 = blockIdx.x*4, t = threadIdx.x;
  for (int r = 0; r < 4; r++){
    for (int m4 = t; m4 < NN/4; m4 += 256){
      float4 v = *(const float4*)&Tk[(size_t)(i0+r)*NN + m4*4];
      tk[r][m4*4+0] = v.x; tk[r][m4*4+1] = v.y; tk[r][m4*4+2] = v.z; tk[r][m4*4+3] = v.w;
    }
  }
  __syncthreads();
  for (int j = t; j < NN; j += 256){
    int n = cnt[j];
    const int*   im = &cscm[j*CAP];
    const float* iv = &cscv[j*CAP];
    float a0=0.f,a1=0.f,a2=0.f,a3=0.f;
    for (int c = 0; c < n; c++){
      int m = im[c]; float v = iv[c];
      a0 += v*tk[0][m]; a1 += v*tk[1][m]; a2 += v*tk[2][m]; a3 += v*tk[3][m];
    }
    Tn[(size_t)(i0+0)*NN + j] = a0;
    Tn[(size_t)(i0+1)*NN + j] = a1;
    Tn[(size_t)(i0+2)*NN + j] = a2;
    Tn[(size_t)(i0+3)*NN + j] = a3;
    if (j == i0+0) rw[j*8 + kidx] = a0;
    if (j == i0+1) rw[j*8 + kidx] = a1;
    if (j == i0+2) rw[j*8 + kidx] = a2;
    if (j == i0+3) rw[j*8 + kidx] = a3;
  }
}

__global__ __launch_bounds__(256) void pe_kernel(const float* __restrict__ rw, const float* __restrict__ W,
                                                 const float* __restrict__ b, float* __restrict__ pe){
  int idx = blockIdx.x*256 + threadIdx.x;
  if (idx >= NN*16) return;
  int i = idx >> 4, c = idx & 15;
  float acc = b[c];
  #pragma unroll
  for (int k = 0; k < 8; k++) acc += rw[i*8+k] * W[k*16+c];
  pe[idx] = acc;
}

__global__ __launch_bounds__(256) void pp_kernel(const float* __restrict__ pe, const float* __restrict__ Wpe,
                                                 const float* __restrict__ bpe, float* __restrict__ pp){
  int idx = blockIdx.x*256 + threadIdx.x;
  if (idx >= 3*NN*12) return;
  int l = idx / (NN*12);
  int rm = idx % (NN*12);
  int j = rm / 12, h = rm % 12;
  float acc = bpe[l*12 + h];
  #pragma unroll
  for (int c = 0; c < 16; c++) acc += pe[j*16+c] * Wpe[(l*16+c)*12 + h];
  pp[idx] = acc;
}

// -------- weight transpose + split-bf16: W[K][N] -> T{hi,lo}[N][K] --------
__global__ __launch_bounds__(256) void wconv(const float* __restrict__ W, unsigned short* __restrict__ Thi,
                                             unsigned short* __restrict__ Tlo, int K, int N){
  __shared__ float ld[32*33];
  int k0 = blockIdx.y*32, n0 = blockIdx.x*32;
  int t = threadIdx.x;
  int r = t>>3, c4 = (t&7)*4;
  float4 v = *(const float4*)&W[(size_t)(k0+r)*N + n0 + c4];
  ld[(c4+0)*33 + r] = v.x; ld[(c4+1)*33 + r] = v.y; ld[(c4+2)*33 + r] = v.z; ld[(c4+3)*33 + r] = v.w;
  __syncthreads();
  u16x4 hi, lo;
  #pragma unroll
  for (int i = 0; i < 4; i++){
    float x = ld[r*33 + c4 + i];
    unsigned short hh = f2bu(x);
    hi[i] = hh;
    lo[i] = f2bu(x - bu2f(hh));
  }
  *(u16x4*)&Thi[(size_t)(n0+r)*K + k0 + c4] = hi;
  *(u16x4*)&Tlo[(size_t)(n0+r)*K + k0 + c4] = lo;
}

// -------- generic f32 -> split bf16 planes (vectorized x4) --------
__global__ __launch_bounds__(256) void split_planes(const float* __restrict__ X,
    unsigned short* __restrict__ Hi, unsigned short* __restrict__ Lo, int n4){
  int i = blockIdx.x*256 + threadIdx.x;
  if (i >= n4) return;
  float4 v = ((const float4*)X)[i];
  float xs[4] = {v.x, v.y, v.z, v.w};
  u16x4 hi, lo;
  #pragma unroll
  for (int k = 0; k < 4; k++){
    unsigned short hh = f2bu(xs[k]);
    hi[k] = hh; lo[k] = f2bu(xs[k] - bu2f(hh));
  }
  ((u16x4*)Hi)[i] = hi;
  ((u16x4*)Lo)[i] = lo;
}

// -------- split-bf16 MFMA GEMM, A as pre-split planes --------
// DOGELU=1: exact GELU epilogue + plane output (Chi/Clo); else f32 C.
template<int DOGELU, int MREP, int NREP>
__global__ __launch_bounds__(256) void gemm_mfma(
    const unsigned short* __restrict__ Ahi, const unsigned short* __restrict__ Alo,
    const unsigned short* __restrict__ BThi, const unsigned short* __restrict__ BTlo,
    const float* __restrict__ bias, float* __restrict__ C,
    unsigned short* __restrict__ Chi, unsigned short* __restrict__ Clo, int N, int K){
  constexpr int BM = MREP*32, BN = NREP*32;
  constexpr int APT8 = BM*32/256/8;   // u16x8 chunks per thread per A plane
  constexpr int BPT8 = BN*32/256/8;
  __shared__ __align__(16) unsigned short smem[(2*BM + 2*BN)*32];
  unsigned short* sAhi = smem;
  unsigned short* sAlo = smem + BM*32;
  unsigned short* sBhi = smem + 2*BM*32;
  unsigned short* sBlo = smem + 2*BM*32 + BN*32;
  const int t = threadIdx.x;
  const int bm = blockIdx.y*BM, bn = blockIdx.x*BN;
  const int lane = t & 63;
  const int wv = t >> 6;
  const int mbase = (wv>>1)*(MREP*16), nbase = (wv&1)*(NREP*16);
  const int lr = lane & 15, kg = lane >> 4;
  f32x4 acc[MREP][NREP];
  #pragma unroll
  for (int m = 0; m < MREP; m++)
    #pragma unroll
    for (int n = 0; n < NREP; n++) acc[m][n] = (f32x4){0.f,0.f,0.f,0.f};

  int arow, akb, brow, bkb;
  if constexpr (BM == 128){ arow = t>>1; akb = (t&1)*16; } else { arow = t>>2; akb = (t&3)*8; }
  if constexpr (BN == 128){ brow = t>>1; bkb = (t&1)*16; } else { brow = t>>2; bkb = (t&3)*8; }

  for (int k0 = 0; k0 < K; k0 += 32){
    u16x8 fah[APT8], fal[APT8], fbh[BPT8], fbl[BPT8];
    const unsigned short* pAh = &Ahi[(size_t)(bm+arow)*K + k0 + akb];
    const unsigned short* pAl = &Alo[(size_t)(bm+arow)*K + k0 + akb];
    #pragma unroll
    for (int i = 0; i < APT8; i++){
      fah[i] = *(const u16x8*)&pAh[i*8];
      fal[i] = *(const u16x8*)&pAl[i*8];
    }
    const unsigned short* pBh = &BThi[(size_t)(bn+brow)*K + k0 + bkb];
    const unsigned short* pBl = &BTlo[(size_t)(bn+brow)*K + k0 + bkb];
    #pragma unroll
    for (int i = 0; i < BPT8; i++){
      fbh[i] = *(const u16x8*)&pBh[i*8];
      fbl[i] = *(const u16x8*)&pBl[i*8];
    }
    __syncthreads();
    #pragma unroll
    for (int g = 0; g < APT8; g++){
      int kgw = (akb>>3) + g;
      *(u16x8*)&sAhi[swz8(arow, kgw)] = fah[g];
      *(u16x8*)&sAlo[swz8(arow, kgw)] = fal[g];
    }
    #pragma unroll
    for (int g = 0; g < BPT8; g++){
      int kgw = (bkb>>3) + g;
      *(u16x8*)&sBhi[swz8(brow, kgw)] = fbh[g];
      *(u16x8*)&sBlo[swz8(brow, kgw)] = fbl[g];
    }
    __syncthreads();
    bf16x8 ah[MREP], al[MREP], bh[NREP], bl[NREP];
    #pragma unroll
    for (int m = 0; m < MREP; m++){
      int o = swz8(mbase + m*16 + lr, kg);
      ah[m] = *(bf16x8*)&sAhi[o];
      al[m] = *(bf16x8*)&sAlo[o];
    }
    #pragma unroll
    for (int n = 0; n < NREP; n++){
      int o = swz8(nbase + n*16 + lr, kg);
      bh[n] = *(bf16x8*)&sBhi[o];
      bl[n] = *(bf16x8*)&sBlo[o];
    }
    #pragma unroll
    for (int m = 0; m < MREP; m++)
      #pragma unroll
      for (int n = 0; n < NREP; n++){
        acc[m][n] = __builtin_amdgcn_mfma_f32_16x16x32_bf16(ah[m], bh[n], acc[m][n], 0, 0, 0);
        acc[m][n] = __builtin_amdgcn_mfma_f32_16x16x32_bf16(al[m], bh[n], acc[m][n], 0, 0, 0);
        acc[m][n] = __builtin_amdgcn_mfma_f32_16x16x32_bf16(ah[m], bl[n], acc[m][n], 0, 0, 0);
      }
  }
  #pragma unroll
  for (int m = 0; m < MREP; m++)
    #pragma unroll
    for (int n = 0; n < NREP; n++){
      int col = bn + nbase + n*16 + lr;
      int row0 = bm + mbase + m*16 + kg*4;
      float bb = bias[col];
      #pragma unroll
      for (int j = 0; j < 4; j++){
        float o = acc[m][n][j] + bb;
        size_t idx = (size_t)(row0+j)*N + col;
        if constexpr (DOGELU){
          o = 0.5f*o*(1.f + erff(o*0.70710678118f));
          unsigned short hh = f2bu(o);
          Chi[idx] = hh;
          Clo[idx] = f2bu(o - bu2f(hh));
        } else {
          C[idx] = o;
        }
      }
    }
}

// -------- qkv -> per-head split planes; V transposed; Q pre-scaled by scale*log2e --------
__global__ __launch_bounds__(256) void qkv_planes(const float* __restrict__ qkv,
    unsigned short* __restrict__ qhi, unsigned short* __restrict__ qlo,
    unsigned short* __restrict__ khi, unsigned short* __restrict__ klo,
    unsigned short* __restrict__ vthi, unsigned short* __restrict__ vtlo){
  __shared__ float vb[64*69];
  const int h = blockIdx.y, j0 = blockIdx.x*64;
  const int t = threadIdx.x;
  const int jl = t >> 4, d4 = (t & 15)*4;
  const float qsc = 0.125f * LOG2E;
  #pragma unroll
  for (int p = 0; p < 4; p++){
    int j = jl + p*16;
    const float* row = &qkv[(size_t)(j0 + j)*2304 + h*64 + d4];
    float4 q4 = *(const float4*)&row[0];
    float4 k4 = *(const float4*)&row[768];
    float4 v4 = *(const float4*)&row[1536];
    float qv[4] = {q4.x*qsc, q4.y*qsc, q4.z*qsc, q4.w*qsc};
    float kv[4] = {k4.x, k4.y, k4.z, k4.w};
    float vv[4] = {v4.x, v4.y, v4.z, v4.w};
    u16x4 qh_, ql_, kh_, kl_;
    #pragma unroll
    for (int i = 0; i < 4; i++){
      unsigned short hh = f2bu(qv[i]); qh_[i] = hh; ql_[i] = f2bu(qv[i] - bu2f(hh));
      hh = f2bu(kv[i]); kh_[i] = hh; kl_[i] = f2bu(kv[i] - bu2f(hh));
      vb[j*69 + d4 + i] = vv[i];
    }
    size_t ob = ((size_t)h*NN + j0 + j)*64 + d4;
    *(u16x4*)&qhi[ob] = qh_; *(u16x4*)&qlo[ob] = ql_;
    *(u16x4*)&khi[ob] = kh_; *(u16x4*)&klo[ob] = kl_;
  }
  __syncthreads();
  #pragma unroll
  for (int p = 0; p < 4; p++){
    int d = jl + p*16;
    u16x4 vh_, vl_;
    #pragma unroll
    for (int i = 0; i < 4; i++){
      float x = vb[(d4+i)*69 + d];
      unsigned short hh = f2bu(x);
      vh_[i] = hh; vl_[i] = f2bu(x - bu2f(hh));
    }
    size_t ob = ((size_t)h*64 + d)*NN + j0 + d4;
    *(u16x4*)&vthi[ob] = vh_;
    *(u16x4*)&vtlo[ob] = vl_;
  }
}

// ---------------- MFMA flash attention (log2-domain softmax, P aliases K-hi) ----------------
__global__ __launch_bounds__(256) void attn_mfma(
    const unsigned short* __restrict__ qhi, const unsigned short* __restrict__ qlo,
    const unsigned short* __restrict__ khi, const unsigned short* __restrict__ klo,
    const unsigned short* __restrict__ vthi, const unsigned short* __restrict__ vtlo,
    const float* __restrict__ pp, float* __restrict__ opart,
    float* __restrict__ mbuf, float* __restrict__ lbuf){
  __shared__ __align__(16) unsigned short sKhi[64*64], sKlo[64*64];
  __shared__ __align__(16) unsigned short sVhi[64*64], sVlo[64*64];
  __shared__ float ppj[64];
  unsigned short* sP = sKhi;   // P^T aliases K-hi (wave-private q strips) after QK^T
  const int h = blockIdx.y, i0 = blockIdx.x*64, z = blockIdx.z;
  const int t = threadIdx.x, l = t & 63, w = t >> 6;
  const int lr = l & 15, lg = l >> 4;
  const int q0w = w*16;
  const int qrow = i0 + q0w + lr;
  bf16x8 qh[2], ql[2];
  #pragma unroll
  for (int ks = 0; ks < 2; ks++){
    size_t qo = ((size_t)h*NN + qrow)*64 + (ks*4 + lg)*8;
    qh[ks] = *(const bf16x8*)&qhi[qo];
    ql[ks] = *(const bf16x8*)&qlo[qo];
  }
  float mrow = -1e30f, lrow = 0.f;
  f32x4 oacc[4];
  #pragma unroll
  for (int dt = 0; dt < 4; dt++) oacc[dt] = (f32x4){0.f,0.f,0.f,0.f};

  for (int jt = 0; jt < 16; jt++){
    const int jb = z*(NN/2) + jt*64;
    __syncthreads();   // prior tile's PV reads (P in sKhi, V) complete
    {
      size_t kb = ((size_t)h*NN + jb + l)*64;
      size_t vbg = ((size_t)h*64 + l)*NN + jb;
      #pragma unroll
      for (int i = 0; i < 2; i++){
        int dg = w*2 + i;
        *(u16x8*)&sKhi[swzA(l, dg)] = *(const u16x8*)&khi[kb + dg*8];
        *(u16x8*)&sKlo[swzA(l, dg)] = *(const u16x8*)&klo[kb + dg*8];
        *(u16x8*)&sVhi[swzA(l, dg)] = *(const u16x8*)&vthi[vbg + dg*8];
        *(u16x8*)&sVlo[swzA(l, dg)] = *(const u16x8*)&vtlo[vbg + dg*8];
      }
      if (t < 64) ppj[t] = pp[(size_t)(jb + t)*12 + h] * LOG2E;
    }
    __syncthreads();
    // ---- QK^T: S^T[j][q] (log2-scaled by construction) ----
    f32x4 sa[4];
    #pragma unroll
    for (int j4 = 0; j4 < 4; j4++) sa[j4] = (f32x4){0.f,0.f,0.f,0.f};
    #pragma unroll
    for (int j4 = 0; j4 < 4; j4++){
      #pragma unroll
      for (int ks = 0; ks < 2; ks++){
        int ro = j4*16 + lr, dg = ks*4 + lg;
        bf16x8 kh = *(const bf16x8*)&sKhi[swzA(ro, dg)];
        bf16x8 kl = *(const bf16x8*)&sKlo[swzA(ro, dg)];
        sa[j4] = __builtin_amdgcn_mfma_f32_16x16x32_bf16(kh, qh[ks], sa[j4], 0, 0, 0);
        sa[j4] = __builtin_amdgcn_mfma_f32_16x16x32_bf16(kl, qh[ks], sa[j4], 0, 0, 0);
        sa[j4] = __builtin_amdgcn_mfma_f32_16x16x32_bf16(kh, ql[ks], sa[j4], 0, 0, 0);
      }
    }
    // ---- bias + online softmax in log2 domain ----
    float mx = -1e30f;
    #pragma unroll
    for (int j4 = 0; j4 < 4; j4++)
      #pragma unroll
      for (int r = 0; r < 4; r++){
        sa[j4][r] += ppj[j4*16 + lg*4 + r];
        mx = fmaxf(mx, sa[j4][r]);
      }
    mx = fmaxf(mx, __shfl_xor(mx, 16, 64));
    mx = fmaxf(mx, __shfl_xor(mx, 32, 64));
    float mn = fmaxf(mrow, mx);
    float alq = __builtin_amdgcn_exp2f(mrow - mn);
    mrow = mn;
    float rs = 0.f;
    #pragma unroll
    for (int j4 = 0; j4 < 4; j4++)
      #pragma unroll
      for (int r = 0; r < 4; r++){
        float pv = __builtin_amdgcn_exp2f(sa[j4][r] - mn);
        sa[j4][r] = pv;
        rs += pv;
      }
    rs += __shfl_xor(rs, 16, 64);
    rs += __shfl_xor(rs, 32, 64);
    lrow = lrow*alq + rs;
    #pragma unroll
    for (int dt = 0; dt < 4; dt++)
      #pragma unroll
      for (int r = 0; r < 4; r++) oacc[dt][r] *= alq;
    __syncthreads();   // all QK^T reads of sKhi done before P overwrite
    // ---- packed P^T store (bf16 hi only), b64 per j4 ----
    {
      int q = q0w + lr;
      #pragma unroll
      for (int j4 = 0; j4 < 4; j4++){
        int jgrp = j4*2 + (lg>>1);
        int o = q*64 + ((jgrp ^ (q&7))<<3) + (lg&1)*4;
        u16x4 pk;
        #pragma unroll
        for (int r = 0; r < 4; r++) pk[r] = f2bu(sa[j4][r]);
        *(u16x4*)&sP[o] = pk;
      }
    }
    // ---- PV: O^T[d][q] += V^T[d][j] P^T[j][q]  (full-V x bf16-P) ----
    #pragma unroll
    for (int ks = 0; ks < 2; ks++){
      int q = q0w + lr, dg = ks*4 + lg;
      bf16x8 pf = *(const bf16x8*)&sP[swzA(q, dg)];
      #pragma unroll
      for (int dt = 0; dt < 4; dt++){
        int dr = dt*16 + lr;
        bf16x8 vh = *(const bf16x8*)&sVhi[swzA(dr, dg)];
        bf16x8 vl = *(const bf16x8*)&sVlo[swzA(dr, dg)];
        oacc[dt] = __builtin_amdgcn_mfma_f32_16x16x32_bf16(vh, pf, oacc[dt], 0, 0, 0);
        oacc[dt] = __builtin_amdgcn_mfma_f32_16x16x32_bf16(vl, pf, oacc[dt], 0, 0, 0);
      }
    }
  }
  #pragma unroll
  for (int dt = 0; dt < 4; dt++)
    #pragma unroll
    for (int r = 0; r < 4; r++){
      int d = dt*16 + lg*4 + r;
      opart[(((size_t)z*NN + qrow)*12 + h)*64 + d] = oacc[dt][r];
    }
  if (lg == 0){
    mbuf[((size_t)z*NN + qrow)*12 + h] = mrow;
    lbuf[((size_t)z*NN + qrow)*12 + h] = lrow;
  }
}

__global__ __launch_bounds__(256) void attn_merge(const float* __restrict__ opart, const float* __restrict__ mbuf,
                                                  const float* __restrict__ lbuf,
                                                  unsigned short* __restrict__ outHi,
                                                  unsigned short* __restrict__ outLo){
  int idx = blockIdx.x*256 + threadIdx.x;   // over NN*12*64, layout [q][h][d]
  int ih = idx >> 6;
  int q = ih / 12, hh = ih % 12, d = idx & 63;
  float m0 = mbuf[ih], m1 = mbuf[NN*12 + ih];
  float l0 = lbuf[ih], l1 = lbuf[NN*12 + ih];
  float mm = fmaxf(m0, m1);
  float e0 = __builtin_amdgcn_exp2f(m0 - mm), e1 = __builtin_amdgcn_exp2f(m1 - mm);
  float L = l0*e0 + l1*e1;
  float o = (opart[idx]*e0 + opart[(size_t)NN*12*64 + idx]*e1) / L;
  size_t oi = (size_t)q*768 + hh*64 + d;
  unsigned short hb_ = f2bu(o);
  outHi[oi] = hb_;
  outLo[oi] = f2bu(o - bu2f(hb_));
}

// ---------------- residual add + LayerNorm (+ split-plane emission) ----------------
__global__ __launch_bounds__(256) void add_ln(const float* __restrict__ X, const float* __restrict__ R,
                                              const float* __restrict__ g, const float* __restrict__ b,
                                              float* __restrict__ Y,
                                              unsigned short* __restrict__ Yhi,
                                              unsigned short* __restrict__ Ylo){
  __shared__ float sbuf[4];
  int i = blockIdx.x, t = threadIdx.x;
  float x0 = X[(size_t)i*768 + t]       + R[(size_t)i*768 + t];
  float x1 = X[(size_t)i*768 + t + 256] + R[(size_t)i*768 + t + 256];
  float x2 = X[(size_t)i*768 + t + 512] + R[(size_t)i*768 + t + 512];
  float s = x0 + x1 + x2;
  for (int w = 32; w >= 1; w >>= 1) s += __shfl_xor(s, w, 64);
  if ((t & 63) == 0) sbuf[t >> 6] = s;
  __syncthreads();
  s = sbuf[0] + sbuf[1] + sbuf[2] + sbuf[3];
  float mean = s * (1.0f/768.0f);
  float d0 = x0-mean, d1 = x1-mean, d2 = x2-mean;
  float vv = d0*d0 + d1*d1 + d2*d2;
  __syncthreads();
  for (int w = 32; w >= 1; w >>= 1) vv += __shfl_xor(vv, w, 64);
  if ((t & 63) == 0) sbuf[t >> 6] = vv;
  __syncthreads();
  vv = sbuf[0] + sbuf[1] + sbuf[2] + sbuf[3];
  float inv = 1.0f / sqrtf(vv*(1.0f/768.0f) + 1e-5f);
  float y0 = d0*inv*g[t]     + b[t];
  float y1 = d1*inv*g[t+256] + b[t+256];
  float y2 = d2*inv*g[t+512] + b[t+512];
  size_t base = (size_t)i*768 + t;
  Y[base] = y0; Y[base+256] = y1; Y[base+512] = y2;
  unsigned short hh;
  hh = f2bu(y0); Yhi[base]     = hh; Ylo[base]     = f2bu(y0 - bu2f(hh));
  hh = f2bu(y1); Yhi[base+256] = hh; Ylo[base+256] = f2bu(y1 - bu2f(hh));
  hh = f2bu(y2); Yhi[base+512] = hh; Ylo[base+512] = f2bu(y2 - bu2f(hh));
}

// ---------------- launcher ----------------
extern "C" void kernel_launch(void* const* d_in, const int* in_sizes, int n_in,
                              void* d_out, int out_size, void* d_ws, size_t ws_size,
                              hipStream_t stream) {
  const float* nf     = (const float*)d_in[0];
  const int*   ei     = (const int*)  d_in[1];
  const float* W_rwpe = (const float*)d_in[2];
  const float* b_rwpe = (const float*)d_in[3];
  const float* Wqkv   = (const float*)d_in[4];
  const float* bqkv   = (const float*)d_in[5];
  const float* Wpe    = (const float*)d_in[6];
  const float* bpe    = (const float*)d_in[7];
  const float* Wout   = (const float*)d_in[8];
  const float* bout   = (const float*)d_in[9];
  const float* W1     = (const float*)d_in[10];
  const float* b1     = (const float*)d_in[11];
  const float* W2     = (const float*)d_in[12];
  const float* b2     = (const float*)d_in[13];
  const float* g1     = (const float*)d_in[14];
  const float* be1    = (const float*)d_in[15];
  const float* g2     = (const float*)d_in[16];
  const float* be2    = (const float*)d_in[17];
  float* out = (float*)d_out;
  (void)in_sizes; (void)n_in; (void)out_size; (void)ws_size;

  char* base = (char*)d_ws;
  size_t off = 0;
  auto alloc = [&](size_t bytes){ void* p = base + off; off += (bytes + 255) & ~(size_t)255; return p; };

  const size_t PL = 7077888ULL;             // split-weight elems per layer
  const size_t oQ = 0, oO = 1769472ULL, oW1 = 2359296ULL, oW2 = 4718592ULL;
  unsigned short* whi = (unsigned short*)alloc(3*PL*2);
  unsigned short* wlo = (unsigned short*)alloc(3*PL*2);
  float* rw  = (float*)alloc((size_t)NN*8*4);
  float* pe  = (float*)alloc((size_t)NN*16*4);
  float* pp  = (float*)alloc((size_t)3*NN*12*4);
  char*  U   = (char*)alloc(92000000ULL);   // union region

  // phase1 views (graph; dead before layer loop)
  float* P0   = (float*)U;
  float* P1   = P0 + (size_t)NN*NN;
  float* cscv = P1 + (size_t)NN*NN;
  int*   cscm = (int*)(cscv + (size_t)NN*CAP);
  int*   cnt  = (int*)(cscm + (size_t)NN*CAP);
  // phase2 views
  float* qkvb    = (float*)U;                                   // NN*2304 f32
  float* opart   = qkvb;                                        // aliases qkvb (dead during attn)
  float* mbuf    = qkvb + (size_t)2*NN*12*64;
  float* lbuf    = mbuf + (size_t)2*NN*12;
  unsigned short* attnbHi = (unsigned short*)(qkvb + (size_t)NN*2304);
  unsigned short* attnbLo = attnbHi + (size_t)NN*768;
  float* projb   = (float*)(attnbLo + (size_t)NN*768);
  float* h1      = projb + (size_t)NN*768;
  unsigned short* h1hi = (unsigned short*)(h1 + (size_t)NN*768);
  unsigned short* h1lo = h1hi + (size_t)NN*768;
  unsigned short* f1hi = h1lo + (size_t)NN*768;                 // NN*3072 u16
  unsigned short* f1lo = f1hi + (size_t)NN*3072;                // NN*3072 u16
  float* ffn2    = (float*)(f1lo + (size_t)NN*3072);
  float* hb      = ffn2 + (size_t)NN*768;
  unsigned short* hbhi = (unsigned short*)(hb + (size_t)NN*768);
  unsigned short* hblo = hbhi + (size_t)NN*768;
  // attn per-head planes alias f1hi region (dead until ffn1 GEMM)
  const size_t PS = (size_t)NN*768;
  unsigned short* qhi_p = f1hi;
  unsigned short* qlo_p = qhi_p + PS;
  unsigned short* khi_p = qhi_p + 2*PS;
  unsigned short* klo_p = qhi_p + 3*PS;
  unsigned short* vthi_p = qhi_p + 4*PS;
  unsigned short* vtlo_p = qhi_p + 5*PS;

  // --- weight pre-split ---
  for (int l = 0; l < 3; l++){
    wconv<<<dim3(2304/32, 768/32), 256, 0, stream>>>(Wqkv + (size_t)l*768*2304, whi + l*PL + oQ,  wlo + l*PL + oQ,  768, 2304);
    wconv<<<dim3(768/32,  768/32), 256, 0, stream>>>(Wout + (size_t)l*768*768,  whi + l*PL + oO,  wlo + l*PL + oO,  768, 768);
    wconv<<<dim3(3072/32, 768/32), 256, 0, stream>>>(W1   + (size_t)l*768*3072, whi + l*PL + oW1, wlo + l*PL + oW1, 768, 3072);
    wconv<<<dim3(768/32, 3072/32), 256, 0, stream>>>(W2   + (size_t)l*3072*768, whi + l*PL + oW2, wlo + l*PL + oW2, 3072, 768);
  }

  // --- RW positional encoding ---
  hipMemsetAsync(P0, 0, (size_t)NN*NN*4, stream);
  scatter_edges<<<EE/256, 256, 0, stream>>>(ei, P0);
  row_norm<<<NN, 256, 0, stream>>>(P0, rw);
  build_csc<<<NN, 256, 0, stream>>>(P0, cscv, cscm, cnt);
  for (int k = 1; k < 8; k++){
    const float* src = (k & 1) ? P0 : P1;
    float*       dst = (k & 1) ? P1 : P0;
    spmm4<<<NN/4, 256, 0, stream>>>(src, cscv, cscm, cnt, dst, rw, k);
  }
  pe_kernel<<<NN*16/256, 256, 0, stream>>>(rw, W_rwpe, b_rwpe, pe);
  pp_kernel<<<3*NN*12/256, 256, 0, stream>>>(pe, Wpe, bpe, pp);

  // --- initial h planes from node features ---
  split_planes<<<(NN*768/4 + 255)/256, 256, 0, stream>>>(nf, hbhi, hblo, NN*768/4);

  // --- transformer layers ---
  const float* hres = nf;
  for (int l = 0; l < 3; l++){
    gemm_mfma<0,4,4><<<dim3(2304/128, 2048/128), 256, 0, stream>>>(hbhi, hblo, whi + l*PL + oQ, wlo + l*PL + oQ, bqkv + (size_t)l*2304, qkvb, nullptr, nullptr, 2304, 768);
    qkv_planes<<<dim3(NN/64, 12), 256, 0, stream>>>(qkvb, qhi_p, qlo_p, khi_p, klo_p, vthi_p, vtlo_p);
    attn_mfma<<<dim3(NN/64, 12, 2), 256, 0, stream>>>(qhi_p, qlo_p, khi_p, klo_p, vthi_p, vtlo_p,
                                                      pp + (size_t)l*NN*12, opart, mbuf, lbuf);
    attn_merge<<<NN*12*64/256, 256, 0, stream>>>(opart, mbuf, lbuf, attnbHi, attnbLo);
    gemm_mfma<0,2,2><<<dim3(768/64, 2048/64), 256, 0, stream>>>(attnbHi, attnbLo, whi + l*PL + oO, wlo + l*PL + oO, bout + (size_t)l*768, projb, nullptr, nullptr, 768, 768);
    add_ln<<<NN, 256, 0, stream>>>(projb, hres, g1 + (size_t)l*768, be1 + (size_t)l*768, h1, h1hi, h1lo);
    gemm_mfma<1,4,4><<<dim3(3072/128, 2048/128), 256, 0, stream>>>(h1hi, h1lo, whi + l*PL + oW1, wlo + l*PL + oW1, b1 + (size_t)l*3072, nullptr, f1hi, f1lo, 3072, 768);
    gemm_mfma<0,2,2><<<dim3(768/64, 2048/64), 256, 0, stream>>>(f1hi, f1lo, whi + l*PL + oW2, wlo + l*PL + oW2, b2 + (size_t)l*768, ffn2, nullptr, nullptr, 768, 3072);
    float* hout = (l == 2) ? out : hb;
    add_ln<<<NN, 256, 0, stream>>>(ffn2, h1, g2 + (size_t)l*768, be2 + (size_t)l*768, hout, hbhi, hblo);
    hres = hb;
  }
}